// Round 8
// baseline (268.863 us; speedup 1.0000x reference)
//
#include <hip/hip_runtime.h>

#define N_NODES   100000
#define N_FEAT    128
#define N_EDGES   1600000
#define HIDDEN    64
#define NUM_GRAPHS 64
#define XPAD 130                              // LDS row stride: bank=(2r+k)%32 -> 2-way (free)
#define CHUNK   8192
#define NCHUNK  ((N_EDGES + CHUNK - 1) / CHUNK)   // 196
#define BSHIFT  8
#define NBUCKET ((N_NODES + 255) >> 8)            // 391 buckets of 256 nodes
#define OFFS_W  (NBUCKET + 1)                     // 392 entries per chunk

typedef unsigned int  uint32;
typedef unsigned short ushort16;

// fp32 -> bf16 round-to-nearest-even
static __device__ __forceinline__ unsigned short f2bf(float f) {
    uint32 u = __float_as_uint(f);
    u += 0x7fffu + ((u >> 16) & 1u);
    return (unsigned short)(u >> 16);
}

// ---------------------------------------------------------------------------
// K1: h = x @ W (bf16 output, fp32 accumulate). lane = row, wave w computes
// cols [16w,16w+16). x in LDS; W via wave-uniform scalar loads.
// ---------------------------------------------------------------------------
__global__ __launch_bounds__(256) void gemm_xw(const float* __restrict__ x,
                                               const float* __restrict__ W,
                                               ushort16* __restrict__ hb) {
    __shared__ float xs[64 * XPAD];            // 33.3 KB
    const int tid  = threadIdx.x;
    const int lane = tid & 63;
    const int wid  = __builtin_amdgcn_readfirstlane(tid >> 6);
    const int c0   = wid * 16;
    const int base = blockIdx.x * 64;

#pragma unroll
    for (int j = 0; j < 8; ++j) {
        const int flat = (tid + j * 256) * 4;
        const int r = flat >> 7, k = flat & 127;
        const int row = base + r;
        float4 v = make_float4(0.f, 0.f, 0.f, 0.f);
        if (row < N_NODES) v = *(const float4*)&x[(size_t)row * N_FEAT + k];
        xs[r * XPAD + k + 0] = v.x;
        xs[r * XPAD + k + 1] = v.y;
        xs[r * XPAD + k + 2] = v.z;
        xs[r * XPAD + k + 3] = v.w;
    }
    __syncthreads();

    float acc[16];
#pragma unroll
    for (int c = 0; c < 16; ++c) acc[c] = 0.f;

    const float* __restrict__ Wp = W + c0;
#pragma unroll 4
    for (int k = 0; k < N_FEAT; ++k) {
        const float xv = xs[lane * XPAD + k];
#pragma unroll
        for (int c = 0; c < 16; ++c)
            acc[c] = fmaf(xv, Wp[k * HIDDEN + c], acc[c]);
    }

    const int row = base + lane;
    if (row < N_NODES) {
        ushort16* hp = &hb[(size_t)row * HIDDEN + c0];
        uint32 o[8];
#pragma unroll
        for (int c = 0; c < 16; c += 2)
            o[c >> 1] = (uint32)f2bf(acc[c]) | ((uint32)f2bf(acc[c + 1]) << 16);
        *(uint4*)&hp[0] = make_uint4(o[0], o[1], o[2], o[3]);
        *(uint4*)&hp[8] = make_uint4(o[4], o[5], o[6], o[7]);
    }
}

// ---------------------------------------------------------------------------
// K2: partition edges into 391 dst-buckets per 8192-edge chunk via LDS; all
// global writes coalesced. dst stored as uint8 in-bucket id (bucket implied
// by segment). Also accumulates bucket sizes (bucket_size pre-zeroed).
// ---------------------------------------------------------------------------
__global__ __launch_bounds__(512) void partition_kernel(const int* __restrict__ ei,
                                                        int* __restrict__ src_out,
                                                        unsigned char* __restrict__ dst8,
                                                        int* __restrict__ offs,
                                                        int* __restrict__ bucket_size) {
    __shared__ int hist[512];
    __shared__ int excl[512];
    __shared__ int ssrc[CHUNK];     // 32 KB
    __shared__ int sdst[CHUNK];     // 32 KB
    const int c = blockIdx.x;
    const int base = c * CHUNK;
    const int n = min(CHUNK, N_EDGES - base);   // always a multiple of 4
    const int t = threadIdx.x;
    hist[t] = 0;
    __syncthreads();

    int es[CHUNK / 512], ed[CHUNK / 512], rk[CHUNK / 512];
#pragma unroll
    for (int k = 0; k < CHUNK / 512; ++k) {
        const int i = t + k * 512;
        if (i < n) {
            ed[k] = __builtin_nontemporal_load(&ei[N_EDGES + base + i]);
            es[k] = __builtin_nontemporal_load(&ei[base + i]);
            rk[k] = atomicAdd(&hist[ed[k] >> BSHIFT], 1);
        }
    }
    __syncthreads();

    const int cnt = hist[t];
    for (int off = 1; off < 512; off <<= 1) {
        const int v = (t >= off) ? hist[t - off] : 0;
        __syncthreads();
        hist[t] += v;
        __syncthreads();
    }
    excl[t] = hist[t] - cnt;
    __syncthreads();
    if (t <= NBUCKET) offs[c * OFFS_W + t] = base + excl[t];   // excl[NBUCKET]==n
    if (t < NBUCKET && cnt > 0) atomicAdd(&bucket_size[t], cnt);

#pragma unroll
    for (int k = 0; k < CHUNK / 512; ++k) {
        const int i = t + k * 512;
        if (i < n) {
            const int pos = excl[ed[k] >> BSHIFT] + rk[k];
            ssrc[pos] = es[k];
            sdst[pos] = ed[k];
        }
    }
    __syncthreads();

    for (int i = t; i < n; i += 512)
        src_out[base + i] = ssrc[i];
    for (int i = t * 4; i < n; i += 2048) {
        const uint32 p = (uint32)(sdst[i] & 255)
                       | ((uint32)(sdst[i + 1] & 255) << 8)
                       | ((uint32)(sdst[i + 2] & 255) << 16)
                       | ((uint32)(sdst[i + 3] & 255) << 24);
        *(uint32*)&dst8[base + i] = p;
    }
}

// ---------------------------------------------------------------------------
// K3: exclusive scan of bucket_size -> bucket_start (1 block).
// ---------------------------------------------------------------------------
__global__ __launch_bounds__(512) void scan_buckets(const int* __restrict__ bucket_size,
                                                    int* __restrict__ bucket_start) {
    __shared__ int s[512];
    const int t = threadIdx.x;
    const int v = (t < NBUCKET) ? bucket_size[t] : 0;
    s[t] = v;
    __syncthreads();
    for (int off = 1; off < 512; off <<= 1) {
        const int a = (t >= off) ? s[t - off] : 0;
        __syncthreads();
        s[t] += a;
        __syncthreads();
    }
    if (t < NBUCKET) bucket_start[t] = s[t] - v;
}

// ---------------------------------------------------------------------------
// K4: per-bucket CSR finalize (pass1 hist -> row_ptr/row_end/dis; pass2
// scatter src into the block-private window, combining in the owning CU's L2).
// ---------------------------------------------------------------------------
__global__ __launch_bounds__(512) void bucket_csr(const int* __restrict__ offs,
                                                  const int* __restrict__ src_tmp,
                                                  const unsigned char* __restrict__ dst8,
                                                  const int* __restrict__ bucket_start,
                                                  int* __restrict__ srcs,
                                                  int* __restrict__ row_ptr,
                                                  int* __restrict__ row_end,
                                                  float* __restrict__ dis) {
    __shared__ int hist[256];
    __shared__ int nxt[256];
    __shared__ int segb[NCHUNK], sege[NCHUNK];
    const int b = blockIdx.x;
    const int lo = b << BSHIFT;
    const int t = threadIdx.x;
    const int lane = t & 63;
    const int wv = t >> 6;                      // 8 waves
    const int bstart = bucket_start[b];

    if (t < 256) hist[t] = 0;
    for (int c = t; c < NCHUNK; c += 512) {
        segb[c] = offs[c * OFFS_W + b];
        sege[c] = offs[c * OFFS_W + b + 1];
    }
    __syncthreads();

    for (int c = wv; c < NCHUNK; c += 8)
        for (int i = segb[c] + lane; i < sege[c]; i += 64)
            atomicAdd(&hist[dst8[i]], 1);
    __syncthreads();

    const int cnt = (t < 256) ? hist[t] : 0;
    for (int off = 1; off < 256; off <<= 1) {
        int v = 0;
        if (t < 256 && t >= off) v = hist[t - off];
        __syncthreads();
        if (t < 256) hist[t] += v;
        __syncthreads();
    }
    if (t < 256) {
        const int excl = hist[t] - cnt;
        nxt[t] = excl;
        const int node = lo + t;
        if (node < N_NODES) {
            row_ptr[node] = bstart + excl;
            row_end[node] = bstart + excl + cnt;
            dis[node]     = rsqrtf((float)cnt + 1.0f);
        }
    }
    __syncthreads();

    for (int c = wv; c < NCHUNK; c += 8)
        for (int i = segb[c] + lane; i < sege[c]; i += 64) {
            const int d = dst8[i];
            const int s = src_tmp[i];
            const int pos = atomicAdd(&nxt[d], 1);
            srcs[bstart + pos] = s;
        }
}

// ---------------------------------------------------------------------------
// K5: per-node gather-aggregate with fused bias+relu+pool. 4 nodes per block
// (N_NODES = 4*25000 exactly). Gathers bf16 h rows (128 B), fp32 accumulate.
// Epilogue stages the 4 relu'd rows in LDS; wave 0 merges graph runs (batch
// sorted) and does one atomic burst per run to u.
// ---------------------------------------------------------------------------
__global__ __launch_bounds__(256) void agg_kernel(const int* __restrict__ row_ptr,
                                                  const int* __restrict__ row_end,
                                                  const int* __restrict__ srcs,
                                                  const ushort16* __restrict__ hb,
                                                  const float* __restrict__ dis,
                                                  const float* __restrict__ bias,
                                                  const int* __restrict__ batch,
                                                  float* __restrict__ u) {
    __shared__ float sp[4][HIDDEN];
    __shared__ int gb[4];
    const int wv   = threadIdx.x >> 6;
    const int node = blockIdx.x * 4 + wv;
    const int lane = threadIdx.x & 63;
    const int q    = lane >> 4;
    const int c4   = (lane & 15) * 4;
    const int beg = row_ptr[node];
    const int end = row_end[node];
    const float dn = dis[node];
    float4 acc = make_float4(0.f, 0.f, 0.f, 0.f);

    for (int j0 = beg; j0 < end; j0 += 64) {
        const int n = min(64, end - j0);
        int s = 0; float w = 0.f;
        if (lane < n) { s = srcs[j0 + lane]; w = dis[s] * dn; }
        const int ng = (n + 3) >> 2;
        for (int i = 0; i < ng; ++i) {
            const int idx = i * 4 + q;
            const int   si = __shfl(s, idx);
            const float wi = __shfl(w, idx);
            const uint2 v = *(const uint2*)&hb[(size_t)si * HIDDEN + c4];
            const float f0 = __uint_as_float(v.x << 16);
            const float f1 = __uint_as_float(v.x & 0xffff0000u);
            const float f2 = __uint_as_float(v.y << 16);
            const float f3 = __uint_as_float(v.y & 0xffff0000u);
            acc.x = fmaf(f0, wi, acc.x);
            acc.y = fmaf(f1, wi, acc.y);
            acc.z = fmaf(f2, wi, acc.z);
            acc.w = fmaf(f3, wi, acc.w);
        }
    }
    acc.x += __shfl_xor(acc.x, 16); acc.y += __shfl_xor(acc.y, 16);
    acc.z += __shfl_xor(acc.z, 16); acc.w += __shfl_xor(acc.w, 16);
    acc.x += __shfl_xor(acc.x, 32); acc.y += __shfl_xor(acc.y, 32);
    acc.z += __shfl_xor(acc.z, 32); acc.w += __shfl_xor(acc.w, 32);

    if (lane == 0) gb[wv] = batch[node];
    if (lane < 16) {
        const uint2 hv = *(const uint2*)&hb[(size_t)node * HIDDEN + c4];
        const float h0 = __uint_as_float(hv.x << 16);
        const float h1 = __uint_as_float(hv.x & 0xffff0000u);
        const float h2 = __uint_as_float(hv.y << 16);
        const float h3 = __uint_as_float(hv.y & 0xffff0000u);
        const float4 bv = *(const float4*)&bias[c4];
        const float d2 = dn * dn;
        float4 r;
        r.x = fmaxf(fmaf(h0, d2, acc.x) + bv.x, 0.f);
        r.y = fmaxf(fmaf(h1, d2, acc.y) + bv.y, 0.f);
        r.z = fmaxf(fmaf(h2, d2, acc.z) + bv.z, 0.f);
        r.w = fmaxf(fmaf(h3, d2, acc.w) + bv.w, 0.f);
        *(float4*)&sp[wv][c4] = r;
    }
    __syncthreads();

    if (threadIdx.x < 64) {
        const int t = threadIdx.x;
        const int g0 = gb[0], g1 = gb[1], g2 = gb[2], g3 = gb[3];
        const float s0 = sp[0][t], s1 = sp[1][t], s2 = sp[2][t], s3 = sp[3][t];
        if (g0 == g3) {                      // sorted -> all four equal
            atomicAdd(&u[g0 * HIDDEN + t], (s0 + s1) + (s2 + s3));
        } else {                             // graph boundary (rare)
            float a = s0; int cg = g0;
            if (g1 == cg) a += s1; else { atomicAdd(&u[cg * HIDDEN + t], a); cg = g1; a = s1; }
            if (g2 == cg) a += s2; else { atomicAdd(&u[cg * HIDDEN + t], a); cg = g2; a = s2; }
            if (g3 == cg) a += s3; else { atomicAdd(&u[cg * HIDDEN + t], a); cg = g3; a = s3; }
            atomicAdd(&u[cg * HIDDEN + t], a);
        }
    }
}

// ---------------------------------------------------------------------------
// K6: out[g] = relu(u[g] @ W1 + b1) @ W2 + b2
// ---------------------------------------------------------------------------
__global__ __launch_bounds__(64) void mlp_kernel(const float* __restrict__ u,
                                                 const float* __restrict__ W1,
                                                 const float* __restrict__ b1,
                                                 const float* __restrict__ W2,
                                                 const float* __restrict__ b2,
                                                 float* __restrict__ out) {
    __shared__ float W1s[HIDDEN * 16];
    __shared__ float W2s[16];
    __shared__ float b1s[16];
    const int t = threadIdx.x;
    for (int i = t; i < HIDDEN * 16; i += 64) W1s[i] = W1[i];
    if (t < 16) { W2s[t] = W2[t]; b1s[t] = b1[t]; }
    __syncthreads();
    if (t < NUM_GRAPHS) {
        float uu[HIDDEN];
#pragma unroll
        for (int k = 0; k < HIDDEN; ++k) uu[k] = u[t * HIDDEN + k];
        float o = b2[0];
#pragma unroll
        for (int j = 0; j < 16; ++j) {
            float s = b1s[j];
#pragma unroll
            for (int k = 0; k < HIDDEN; ++k) s = fmaf(uu[k], W1s[k * 16 + j], s);
            o = fmaf(fmaxf(s, 0.f), W2s[j], o);
        }
        out[t] = o;
    }
}

// ---------------------------------------------------------------------------
extern "C" void kernel_launch(void* const* d_in, const int* in_sizes, int n_in,
                              void* d_out, int out_size, void* d_ws, size_t ws_size,
                              hipStream_t stream) {
    const float* x  = (const float*)d_in[0];
    const float* W  = (const float*)d_in[1];
    const float* b  = (const float*)d_in[2];
    const float* W1 = (const float*)d_in[3];
    const float* b1 = (const float*)d_in[4];
    const float* W2 = (const float*)d_in[5];
    const float* b2 = (const float*)d_in[6];
    const int*   ei = (const int*)d_in[7];     // [2, E] flat
    const int* batch = (const int*)d_in[8];    // [N], sorted
    float* out = (float*)d_out;

    // workspace (~29 MB):
    //   hb       : N*64 bf16   12.8 MB
    //   src_tmp  : E int        6.4 MB
    //   dst8     : E u8         1.6 MB
    //   srcs     : E int        6.4 MB
    //   offs     : 196*392 int  0.3 MB
    //   row_ptr/row_end/dis     1.2 MB
    //   bucket_size/start/u     tiny
    ushort16* hb       = (ushort16*)d_ws;
    int*      src_tmp  = (int*)(hb + (size_t)N_NODES * HIDDEN);
    unsigned char* dst8 = (unsigned char*)(src_tmp + N_EDGES);
    int*      srcs     = (int*)(dst8 + N_EDGES);      // E multiple of 4 -> aligned
    int*      offs     = srcs + N_EDGES;
    int*      row_ptr  = offs + NCHUNK * OFFS_W;
    int*      row_end  = row_ptr + N_NODES;
    float*    dis      = (float*)(row_end + N_NODES);
    int*      bucket_size  = (int*)(dis + N_NODES);
    int*      bucket_start = bucket_size + 512;
    float*    u        = (float*)(bucket_start + 512);

    hipMemsetAsync(bucket_size, 0, 512 * sizeof(int), stream);
    hipMemsetAsync(u, 0, NUM_GRAPHS * HIDDEN * sizeof(float), stream);

    gemm_xw<<<(N_NODES + 63) / 64, 256, 0, stream>>>(x, W, hb);
    partition_kernel<<<NCHUNK, 512, 0, stream>>>(ei, src_tmp, dst8, offs, bucket_size);
    scan_buckets<<<1, 512, 0, stream>>>(bucket_size, bucket_start);
    bucket_csr<<<NBUCKET, 512, 0, stream>>>(offs, src_tmp, dst8, bucket_start,
                                            srcs, row_ptr, row_end, dis);
    agg_kernel<<<N_NODES / 4, 256, 0, stream>>>(row_ptr, row_end, srcs, hb, dis, b, batch, u);
    mlp_kernel<<<1, 64, 0, stream>>>(u, W1, b1, W2, b2, out);
}

// Round 9
// 261.508 us; speedup vs baseline: 1.0281x; 1.0281x over previous
//
#include <hip/hip_runtime.h>

#define N_NODES   100000
#define N_FEAT    128
#define N_EDGES   1600000
#define HIDDEN    64
#define NUM_GRAPHS 64
#define XPAD 130                              // LDS row stride: bank=(2r+k)%32 -> 2-way (free)
#define CHUNK   8192
#define NCHUNK  ((N_EDGES + CHUNK - 1) / CHUNK)   // 196
#define BSHIFT  8
#define NBUCKET ((N_NODES + 255) >> 8)            // 391 buckets of 256 nodes
#define OFFS_W  (NBUCKET + 1)                     // 392 entries per chunk

typedef unsigned int  uint32;
typedef unsigned short ushort16;

// fp32 -> bf16 round-to-nearest-even
static __device__ __forceinline__ unsigned short f2bf(float f) {
    uint32 u = __float_as_uint(f);
    u += 0x7fffu + ((u >> 16) & 1u);
    return (unsigned short)(u >> 16);
}

// ---------------------------------------------------------------------------
// K1: h = x @ W (bf16 output, fp32 accumulate). lane = row, wave w computes
// cols [16w,16w+16). x in LDS; W via wave-uniform scalar loads.
// ---------------------------------------------------------------------------
__global__ __launch_bounds__(256) void gemm_xw(const float* __restrict__ x,
                                               const float* __restrict__ W,
                                               ushort16* __restrict__ hb) {
    __shared__ float xs[64 * XPAD];            // 33.3 KB
    const int tid  = threadIdx.x;
    const int lane = tid & 63;
    const int wid  = __builtin_amdgcn_readfirstlane(tid >> 6);
    const int c0   = wid * 16;
    const int base = blockIdx.x * 64;

#pragma unroll
    for (int j = 0; j < 8; ++j) {
        const int flat = (tid + j * 256) * 4;
        const int r = flat >> 7, k = flat & 127;
        const int row = base + r;
        float4 v = make_float4(0.f, 0.f, 0.f, 0.f);
        if (row < N_NODES) v = *(const float4*)&x[(size_t)row * N_FEAT + k];
        xs[r * XPAD + k + 0] = v.x;
        xs[r * XPAD + k + 1] = v.y;
        xs[r * XPAD + k + 2] = v.z;
        xs[r * XPAD + k + 3] = v.w;
    }
    __syncthreads();

    float acc[16];
#pragma unroll
    for (int c = 0; c < 16; ++c) acc[c] = 0.f;

    const float* __restrict__ Wp = W + c0;
#pragma unroll 4
    for (int k = 0; k < N_FEAT; ++k) {
        const float xv = xs[lane * XPAD + k];
#pragma unroll
        for (int c = 0; c < 16; ++c)
            acc[c] = fmaf(xv, Wp[k * HIDDEN + c], acc[c]);
    }

    const int row = base + lane;
    if (row < N_NODES) {
        ushort16* hp = &hb[(size_t)row * HIDDEN + c0];
        uint32 o[8];
#pragma unroll
        for (int c = 0; c < 16; c += 2)
            o[c >> 1] = (uint32)f2bf(acc[c]) | ((uint32)f2bf(acc[c + 1]) << 16);
        *(uint4*)&hp[0] = make_uint4(o[0], o[1], o[2], o[3]);
        *(uint4*)&hp[8] = make_uint4(o[4], o[5], o[6], o[7]);
    }
}

// ---------------------------------------------------------------------------
// K2: partition edges into 391 dst-buckets per 8192-edge chunk via LDS; all
// global writes coalesced. dst stored as uint8 in-bucket id (bucket implied
// by segment). Also accumulates bucket sizes (bucket_size pre-zeroed).
// ---------------------------------------------------------------------------
__global__ __launch_bounds__(512) void partition_kernel(const int* __restrict__ ei,
                                                        int* __restrict__ src_out,
                                                        unsigned char* __restrict__ dst8,
                                                        int* __restrict__ offs,
                                                        int* __restrict__ bucket_size) {
    __shared__ int hist[512];
    __shared__ int excl[512];
    __shared__ int ssrc[CHUNK];     // 32 KB
    __shared__ int sdst[CHUNK];     // 32 KB
    const int c = blockIdx.x;
    const int base = c * CHUNK;
    const int n = min(CHUNK, N_EDGES - base);   // always a multiple of 4
    const int t = threadIdx.x;
    hist[t] = 0;
    __syncthreads();

    int es[CHUNK / 512], ed[CHUNK / 512], rk[CHUNK / 512];
#pragma unroll
    for (int k = 0; k < CHUNK / 512; ++k) {
        const int i = t + k * 512;
        if (i < n) {
            ed[k] = __builtin_nontemporal_load(&ei[N_EDGES + base + i]);
            es[k] = __builtin_nontemporal_load(&ei[base + i]);
            rk[k] = atomicAdd(&hist[ed[k] >> BSHIFT], 1);
        }
    }
    __syncthreads();

    const int cnt = hist[t];
    for (int off = 1; off < 512; off <<= 1) {
        const int v = (t >= off) ? hist[t - off] : 0;
        __syncthreads();
        hist[t] += v;
        __syncthreads();
    }
    excl[t] = hist[t] - cnt;
    __syncthreads();
    if (t <= NBUCKET) offs[c * OFFS_W + t] = base + excl[t];   // excl[NBUCKET]==n
    if (t < NBUCKET && cnt > 0) atomicAdd(&bucket_size[t], cnt);

#pragma unroll
    for (int k = 0; k < CHUNK / 512; ++k) {
        const int i = t + k * 512;
        if (i < n) {
            const int pos = excl[ed[k] >> BSHIFT] + rk[k];
            ssrc[pos] = es[k];
            sdst[pos] = ed[k];
        }
    }
    __syncthreads();

    for (int i = t; i < n; i += 512)
        src_out[base + i] = ssrc[i];
    for (int i = t * 4; i < n; i += 2048) {
        const uint32 p = (uint32)(sdst[i] & 255)
                       | ((uint32)(sdst[i + 1] & 255) << 8)
                       | ((uint32)(sdst[i + 2] & 255) << 16)
                       | ((uint32)(sdst[i + 3] & 255) << 24);
        *(uint32*)&dst8[base + i] = p;
    }
}

// ---------------------------------------------------------------------------
// K3: exclusive scan of bucket_size -> bucket_start (1 block).
// ---------------------------------------------------------------------------
__global__ __launch_bounds__(512) void scan_buckets(const int* __restrict__ bucket_size,
                                                    int* __restrict__ bucket_start) {
    __shared__ int s[512];
    const int t = threadIdx.x;
    const int v = (t < NBUCKET) ? bucket_size[t] : 0;
    s[t] = v;
    __syncthreads();
    for (int off = 1; off < 512; off <<= 1) {
        const int a = (t >= off) ? s[t - off] : 0;
        __syncthreads();
        s[t] += a;
        __syncthreads();
    }
    if (t < NBUCKET) bucket_start[t] = s[t] - v;
}

// ---------------------------------------------------------------------------
// K4: per-bucket CSR finalize (pass1 hist -> row_ptr/row_end/dis; pass2
// scatter src into the block-private window, combining in the owning CU's L2).
// ---------------------------------------------------------------------------
__global__ __launch_bounds__(512) void bucket_csr(const int* __restrict__ offs,
                                                  const int* __restrict__ src_tmp,
                                                  const unsigned char* __restrict__ dst8,
                                                  const int* __restrict__ bucket_start,
                                                  int* __restrict__ srcs,
                                                  int* __restrict__ row_ptr,
                                                  int* __restrict__ row_end,
                                                  float* __restrict__ dis) {
    __shared__ int hist[256];
    __shared__ int nxt[256];
    __shared__ int segb[NCHUNK], sege[NCHUNK];
    const int b = blockIdx.x;
    const int lo = b << BSHIFT;
    const int t = threadIdx.x;
    const int lane = t & 63;
    const int wv = t >> 6;                      // 8 waves
    const int bstart = bucket_start[b];

    if (t < 256) hist[t] = 0;
    for (int c = t; c < NCHUNK; c += 512) {
        segb[c] = offs[c * OFFS_W + b];
        sege[c] = offs[c * OFFS_W + b + 1];
    }
    __syncthreads();

    for (int c = wv; c < NCHUNK; c += 8)
        for (int i = segb[c] + lane; i < sege[c]; i += 64)
            atomicAdd(&hist[dst8[i]], 1);
    __syncthreads();

    const int cnt = (t < 256) ? hist[t] : 0;
    for (int off = 1; off < 256; off <<= 1) {
        int v = 0;
        if (t < 256 && t >= off) v = hist[t - off];
        __syncthreads();
        if (t < 256) hist[t] += v;
        __syncthreads();
    }
    if (t < 256) {
        const int excl = hist[t] - cnt;
        nxt[t] = excl;
        const int node = lo + t;
        if (node < N_NODES) {
            row_ptr[node] = bstart + excl;
            row_end[node] = bstart + excl + cnt;
            dis[node]     = rsqrtf((float)cnt + 1.0f);
        }
    }
    __syncthreads();

    for (int c = wv; c < NCHUNK; c += 8)
        for (int i = segb[c] + lane; i < sege[c]; i += 64) {
            const int d = dst8[i];
            const int s = src_tmp[i];
            const int pos = atomicAdd(&nxt[d], 1);
            srcs[bstart + pos] = s;
        }
}

// ---------------------------------------------------------------------------
// K5: per-node gather-aggregate, MLP-widened: 8 lanes per edge, each lane
// loads uint4 (16 B = 8 bf16 cols) -> 8 edges / 16 cache lines outstanding
// per wave-instruction (R8's 8B loads halved MLP and halved throughput).
// Fused bias+relu+pool epilogue (batch sorted).
// ---------------------------------------------------------------------------
__global__ __launch_bounds__(256) void agg_kernel(const int* __restrict__ row_ptr,
                                                  const int* __restrict__ row_end,
                                                  const int* __restrict__ srcs,
                                                  const ushort16* __restrict__ hb,
                                                  const float* __restrict__ dis,
                                                  const float* __restrict__ bias,
                                                  const int* __restrict__ batch,
                                                  float* __restrict__ u) {
    __shared__ float sp[4][HIDDEN];
    __shared__ int gb[4];
    const int wv   = threadIdx.x >> 6;
    const int node = blockIdx.x * 4 + wv;
    const int lane = threadIdx.x & 63;
    const int g8   = lane >> 3;        // edge subgroup 0..7
    const int c8   = (lane & 7) * 8;   // column group (8 cols)
    const int beg = row_ptr[node];
    const int end = row_end[node];
    const float dn = dis[node];
    float acc[8];
#pragma unroll
    for (int k = 0; k < 8; ++k) acc[k] = 0.f;

    for (int j0 = beg; j0 < end; j0 += 64) {
        const int n = min(64, end - j0);
        int s = 0; float w = 0.f;
        if (lane < n) { s = srcs[j0 + lane]; w = dis[s] * dn; }
        const int ng = (n + 7) >> 3;
        for (int i = 0; i < ng; ++i) {
            const int idx = i * 8 + g8;          // edge in chunk (w=0 pads tail)
            const int   si = __shfl(s, idx);
            const float wi = __shfl(w, idx);
            const uint4 v = *(const uint4*)&hb[(size_t)si * HIDDEN + c8];
            acc[0] = fmaf(__uint_as_float(v.x << 16),        wi, acc[0]);
            acc[1] = fmaf(__uint_as_float(v.x & 0xffff0000u), wi, acc[1]);
            acc[2] = fmaf(__uint_as_float(v.y << 16),        wi, acc[2]);
            acc[3] = fmaf(__uint_as_float(v.y & 0xffff0000u), wi, acc[3]);
            acc[4] = fmaf(__uint_as_float(v.z << 16),        wi, acc[4]);
            acc[5] = fmaf(__uint_as_float(v.z & 0xffff0000u), wi, acc[5]);
            acc[6] = fmaf(__uint_as_float(v.w << 16),        wi, acc[6]);
            acc[7] = fmaf(__uint_as_float(v.w & 0xffff0000u), wi, acc[7]);
        }
    }
    // sum the 8 edge-subgroup partials: lanes sharing (lane&7) hold same cols
#pragma unroll
    for (int k = 0; k < 8; ++k) {
        acc[k] += __shfl_xor(acc[k], 8);
        acc[k] += __shfl_xor(acc[k], 16);
        acc[k] += __shfl_xor(acc[k], 32);
    }

    if (lane == 0) gb[wv] = batch[node];
    if (lane < 8) {
        const uint4 hv = *(const uint4*)&hb[(size_t)node * HIDDEN + c8];
        const float d2 = dn * dn;
        float hs[8];
        hs[0] = __uint_as_float(hv.x << 16); hs[1] = __uint_as_float(hv.x & 0xffff0000u);
        hs[2] = __uint_as_float(hv.y << 16); hs[3] = __uint_as_float(hv.y & 0xffff0000u);
        hs[4] = __uint_as_float(hv.z << 16); hs[5] = __uint_as_float(hv.z & 0xffff0000u);
        hs[6] = __uint_as_float(hv.w << 16); hs[7] = __uint_as_float(hv.w & 0xffff0000u);
        const float4 b0 = *(const float4*)&bias[c8];
        const float4 b1 = *(const float4*)&bias[c8 + 4];
        float4 r0, r1;
        r0.x = fmaxf(fmaf(hs[0], d2, acc[0]) + b0.x, 0.f);
        r0.y = fmaxf(fmaf(hs[1], d2, acc[1]) + b0.y, 0.f);
        r0.z = fmaxf(fmaf(hs[2], d2, acc[2]) + b0.z, 0.f);
        r0.w = fmaxf(fmaf(hs[3], d2, acc[3]) + b0.w, 0.f);
        r1.x = fmaxf(fmaf(hs[4], d2, acc[4]) + b1.x, 0.f);
        r1.y = fmaxf(fmaf(hs[5], d2, acc[5]) + b1.y, 0.f);
        r1.z = fmaxf(fmaf(hs[6], d2, acc[6]) + b1.z, 0.f);
        r1.w = fmaxf(fmaf(hs[7], d2, acc[7]) + b1.w, 0.f);
        *(float4*)&sp[wv][c8]     = r0;
        *(float4*)&sp[wv][c8 + 4] = r1;
    }
    __syncthreads();

    if (threadIdx.x < 64) {
        const int t = threadIdx.x;
        const int g0 = gb[0], g1 = gb[1], g2 = gb[2], g3 = gb[3];
        const float s0 = sp[0][t], s1 = sp[1][t], s2 = sp[2][t], s3 = sp[3][t];
        if (g0 == g3) {                      // sorted -> all four equal
            atomicAdd(&u[g0 * HIDDEN + t], (s0 + s1) + (s2 + s3));
        } else {                             // graph boundary (rare)
            float a = s0; int cg = g0;
            if (g1 == cg) a += s1; else { atomicAdd(&u[cg * HIDDEN + t], a); cg = g1; a = s1; }
            if (g2 == cg) a += s2; else { atomicAdd(&u[cg * HIDDEN + t], a); cg = g2; a = s2; }
            if (g3 == cg) a += s3; else { atomicAdd(&u[cg * HIDDEN + t], a); cg = g3; a = s3; }
            atomicAdd(&u[cg * HIDDEN + t], a);
        }
    }
}

// ---------------------------------------------------------------------------
// K6: out[g] = relu(u[g] @ W1 + b1) @ W2 + b2
// ---------------------------------------------------------------------------
__global__ __launch_bounds__(64) void mlp_kernel(const float* __restrict__ u,
                                                 const float* __restrict__ W1,
                                                 const float* __restrict__ b1,
                                                 const float* __restrict__ W2,
                                                 const float* __restrict__ b2,
                                                 float* __restrict__ out) {
    __shared__ float W1s[HIDDEN * 16];
    __shared__ float W2s[16];
    __shared__ float b1s[16];
    const int t = threadIdx.x;
    for (int i = t; i < HIDDEN * 16; i += 64) W1s[i] = W1[i];
    if (t < 16) { W2s[t] = W2[t]; b1s[t] = b1[t]; }
    __syncthreads();
    if (t < NUM_GRAPHS) {
        float uu[HIDDEN];
#pragma unroll
        for (int k = 0; k < HIDDEN; ++k) uu[k] = u[t * HIDDEN + k];
        float o = b2[0];
#pragma unroll
        for (int j = 0; j < 16; ++j) {
            float s = b1s[j];
#pragma unroll
            for (int k = 0; k < HIDDEN; ++k) s = fmaf(uu[k], W1s[k * 16 + j], s);
            o = fmaf(fmaxf(s, 0.f), W2s[j], o);
        }
        out[t] = o;
    }
}

// ---------------------------------------------------------------------------
extern "C" void kernel_launch(void* const* d_in, const int* in_sizes, int n_in,
                              void* d_out, int out_size, void* d_ws, size_t ws_size,
                              hipStream_t stream) {
    const float* x  = (const float*)d_in[0];
    const float* W  = (const float*)d_in[1];
    const float* b  = (const float*)d_in[2];
    const float* W1 = (const float*)d_in[3];
    const float* b1 = (const float*)d_in[4];
    const float* W2 = (const float*)d_in[5];
    const float* b2 = (const float*)d_in[6];
    const int*   ei = (const int*)d_in[7];     // [2, E] flat
    const int* batch = (const int*)d_in[8];    // [N], sorted
    float* out = (float*)d_out;

    ushort16* hb       = (ushort16*)d_ws;
    int*      src_tmp  = (int*)(hb + (size_t)N_NODES * HIDDEN);
    unsigned char* dst8 = (unsigned char*)(src_tmp + N_EDGES);
    int*      srcs     = (int*)(dst8 + N_EDGES);      // E multiple of 4 -> aligned
    int*      offs     = srcs + N_EDGES;
    int*      row_ptr  = offs + NCHUNK * OFFS_W;
    int*      row_end  = row_ptr + N_NODES;
    float*    dis      = (float*)(row_end + N_NODES);
    int*      bucket_size  = (int*)(dis + N_NODES);
    int*      bucket_start = bucket_size + 512;
    float*    u        = (float*)(bucket_start + 512);

    hipMemsetAsync(bucket_size, 0, 512 * sizeof(int), stream);
    hipMemsetAsync(u, 0, NUM_GRAPHS * HIDDEN * sizeof(float), stream);

    gemm_xw<<<(N_NODES + 63) / 64, 256, 0, stream>>>(x, W, hb);
    partition_kernel<<<NCHUNK, 512, 0, stream>>>(ei, src_tmp, dst8, offs, bucket_size);
    scan_buckets<<<1, 512, 0, stream>>>(bucket_size, bucket_start);
    bucket_csr<<<NBUCKET, 512, 0, stream>>>(offs, src_tmp, dst8, bucket_start,
                                            srcs, row_ptr, row_end, dis);
    agg_kernel<<<N_NODES / 4, 256, 0, stream>>>(row_ptr, row_end, srcs, hb, dis, b, batch, u);
    mlp_kernel<<<1, 64, 0, stream>>>(u, W1, b1, W2, b2, out);
}

// Round 10
// 227.933 us; speedup vs baseline: 1.1796x; 1.1473x over previous
//
#include <hip/hip_runtime.h>

#define N_NODES   100000
#define N_FEAT    128
#define N_EDGES   1600000
#define HIDDEN    64
#define NUM_GRAPHS 64
#define XPAD 130                              // LDS row stride: bank=(2r+k)%32 -> 2-way (free)
#define CHUNK   8192
#define NCHUNK  ((N_EDGES + CHUNK - 1) / CHUNK)   // 196
#define BSHIFT  8
#define NBUCKET ((N_NODES + 255) >> 8)            // 391 buckets of 256 nodes
#define OFFS_W  (NBUCKET + 1)                     // 392 entries per chunk

typedef unsigned int  uint32;
typedef unsigned short ushort16;

// fp32 -> bf16 round-to-nearest-even
static __device__ __forceinline__ unsigned short f2bf(float f) {
    uint32 u = __float_as_uint(f);
    u += 0x7fffu + ((u >> 16) & 1u);
    return (unsigned short)(u >> 16);
}

// ---------------------------------------------------------------------------
// K1: h = x @ W (bf16 output, fp32 accumulate). lane = row, wave w computes
// cols [16w,16w+16). x in LDS; W via wave-uniform scalar loads.
// ---------------------------------------------------------------------------
__global__ __launch_bounds__(256) void gemm_xw(const float* __restrict__ x,
                                               const float* __restrict__ W,
                                               ushort16* __restrict__ hb) {
    __shared__ float xs[64 * XPAD];            // 33.3 KB
    const int tid  = threadIdx.x;
    const int lane = tid & 63;
    const int wid  = __builtin_amdgcn_readfirstlane(tid >> 6);
    const int c0   = wid * 16;
    const int base = blockIdx.x * 64;

#pragma unroll
    for (int j = 0; j < 8; ++j) {
        const int flat = (tid + j * 256) * 4;
        const int r = flat >> 7, k = flat & 127;
        const int row = base + r;
        float4 v = make_float4(0.f, 0.f, 0.f, 0.f);
        if (row < N_NODES) v = *(const float4*)&x[(size_t)row * N_FEAT + k];
        xs[r * XPAD + k + 0] = v.x;
        xs[r * XPAD + k + 1] = v.y;
        xs[r * XPAD + k + 2] = v.z;
        xs[r * XPAD + k + 3] = v.w;
    }
    __syncthreads();

    float acc[16];
#pragma unroll
    for (int c = 0; c < 16; ++c) acc[c] = 0.f;

    const float* __restrict__ Wp = W + c0;
#pragma unroll 4
    for (int k = 0; k < N_FEAT; ++k) {
        const float xv = xs[lane * XPAD + k];
#pragma unroll
        for (int c = 0; c < 16; ++c)
            acc[c] = fmaf(xv, Wp[k * HIDDEN + c], acc[c]);
    }

    const int row = base + lane;
    if (row < N_NODES) {
        ushort16* hp = &hb[(size_t)row * HIDDEN + c0];
        uint32 o[8];
#pragma unroll
        for (int c = 0; c < 16; c += 2)
            o[c >> 1] = (uint32)f2bf(acc[c]) | ((uint32)f2bf(acc[c + 1]) << 16);
        *(uint4*)&hp[0] = make_uint4(o[0], o[1], o[2], o[3]);
        *(uint4*)&hp[8] = make_uint4(o[4], o[5], o[6], o[7]);
    }
}

// ---------------------------------------------------------------------------
// K2: partition edges into 391 dst-buckets per 8192-edge chunk via LDS; all
// global writes coalesced. dst stored as uint8 in-bucket id. Accumulates
// bucket sizes (bucket_size pre-zeroed).
// ---------------------------------------------------------------------------
__global__ __launch_bounds__(512) void partition_kernel(const int* __restrict__ ei,
                                                        int* __restrict__ src_out,
                                                        unsigned char* __restrict__ dst8,
                                                        int* __restrict__ offs,
                                                        int* __restrict__ bucket_size) {
    __shared__ int hist[512];
    __shared__ int excl[512];
    __shared__ int ssrc[CHUNK];     // 32 KB
    __shared__ int sdst[CHUNK];     // 32 KB
    const int c = blockIdx.x;
    const int base = c * CHUNK;
    const int n = min(CHUNK, N_EDGES - base);   // always a multiple of 4
    const int t = threadIdx.x;
    hist[t] = 0;
    __syncthreads();

    int es[CHUNK / 512], ed[CHUNK / 512], rk[CHUNK / 512];
#pragma unroll
    for (int k = 0; k < CHUNK / 512; ++k) {
        const int i = t + k * 512;
        if (i < n) {
            ed[k] = __builtin_nontemporal_load(&ei[N_EDGES + base + i]);
            es[k] = __builtin_nontemporal_load(&ei[base + i]);
            rk[k] = atomicAdd(&hist[ed[k] >> BSHIFT], 1);
        }
    }
    __syncthreads();

    const int cnt = hist[t];
    for (int off = 1; off < 512; off <<= 1) {
        const int v = (t >= off) ? hist[t - off] : 0;
        __syncthreads();
        hist[t] += v;
        __syncthreads();
    }
    excl[t] = hist[t] - cnt;
    __syncthreads();
    if (t <= NBUCKET) offs[c * OFFS_W + t] = base + excl[t];   // excl[NBUCKET]==n
    if (t < NBUCKET && cnt > 0) atomicAdd(&bucket_size[t], cnt);

#pragma unroll
    for (int k = 0; k < CHUNK / 512; ++k) {
        const int i = t + k * 512;
        if (i < n) {
            const int pos = excl[ed[k] >> BSHIFT] + rk[k];
            ssrc[pos] = es[k];
            sdst[pos] = ed[k];
        }
    }
    __syncthreads();

    for (int i = t; i < n; i += 512)
        src_out[base + i] = ssrc[i];
    for (int i = t * 4; i < n; i += 2048) {
        const uint32 p = (uint32)(sdst[i] & 255)
                       | ((uint32)(sdst[i + 1] & 255) << 8)
                       | ((uint32)(sdst[i + 2] & 255) << 16)
                       | ((uint32)(sdst[i + 3] & 255) << 24);
        *(uint32*)&dst8[base + i] = p;
    }
}

// ---------------------------------------------------------------------------
// K3: exclusive scan of bucket_size -> bucket_start (1 block).
// ---------------------------------------------------------------------------
__global__ __launch_bounds__(512) void scan_buckets(const int* __restrict__ bucket_size,
                                                    int* __restrict__ bucket_start) {
    __shared__ int s[512];
    const int t = threadIdx.x;
    const int v = (t < NBUCKET) ? bucket_size[t] : 0;
    s[t] = v;
    __syncthreads();
    for (int off = 1; off < 512; off <<= 1) {
        const int a = (t >= off) ? s[t - off] : 0;
        __syncthreads();
        s[t] += a;
        __syncthreads();
    }
    if (t < NBUCKET) bucket_start[t] = s[t] - v;
}

// ---------------------------------------------------------------------------
// K4: per-bucket CSR finalize (pass1 hist -> row_ptr/row_end/dis; pass2
// scatter src into the block-private window, combining in the owning CU's L2).
// ---------------------------------------------------------------------------
__global__ __launch_bounds__(512) void bucket_csr(const int* __restrict__ offs,
                                                  const int* __restrict__ src_tmp,
                                                  const unsigned char* __restrict__ dst8,
                                                  const int* __restrict__ bucket_start,
                                                  int* __restrict__ srcs,
                                                  int* __restrict__ row_ptr,
                                                  int* __restrict__ row_end,
                                                  float* __restrict__ dis) {
    __shared__ int hist[256];
    __shared__ int nxt[256];
    __shared__ int segb[NCHUNK], sege[NCHUNK];
    const int b = blockIdx.x;
    const int lo = b << BSHIFT;
    const int t = threadIdx.x;
    const int lane = t & 63;
    const int wv = t >> 6;                      // 8 waves
    const int bstart = bucket_start[b];

    if (t < 256) hist[t] = 0;
    for (int c = t; c < NCHUNK; c += 512) {
        segb[c] = offs[c * OFFS_W + b];
        sege[c] = offs[c * OFFS_W + b + 1];
    }
    __syncthreads();

    for (int c = wv; c < NCHUNK; c += 8)
        for (int i = segb[c] + lane; i < sege[c]; i += 64)
            atomicAdd(&hist[dst8[i]], 1);
    __syncthreads();

    const int cnt = (t < 256) ? hist[t] : 0;
    for (int off = 1; off < 256; off <<= 1) {
        int v = 0;
        if (t < 256 && t >= off) v = hist[t - off];
        __syncthreads();
        if (t < 256) hist[t] += v;
        __syncthreads();
    }
    if (t < 256) {
        const int excl = hist[t] - cnt;
        nxt[t] = excl;
        const int node = lo + t;
        if (node < N_NODES) {
            row_ptr[node] = bstart + excl;
            row_end[node] = bstart + excl + cnt;
            dis[node]     = rsqrtf((float)cnt + 1.0f);
        }
    }
    __syncthreads();

    for (int c = wv; c < NCHUNK; c += 8)
        for (int i = segb[c] + lane; i < sege[c]; i += 64) {
            const int d = dst8[i];
            const int s = src_tmp[i];
            const int pos = atomicAdd(&nxt[d], 1);
            srcs[bstart + pos] = s;
        }
}

// ---------------------------------------------------------------------------
// K5: gather-aggregate, 8 nodes per wave for MLP. Lane group g (8 lanes) owns
// node 32*blk+8*wv+g; lane k owns cols [8k,8k+8) (uint4 of bf16). One edge
// per node per iteration -> trip count ~deg of independent 16-line gathers
// (vs ng=deg/8 in R9 -> 4x the loads in flight). No cross-lane reduction:
// each lane's acc[8] is final. Epilogue stages 32 rows in LDS and pools with
// ~1 atomic burst per block (batch sorted).
// ---------------------------------------------------------------------------
__global__ __launch_bounds__(256) void agg_kernel(const int* __restrict__ row_ptr,
                                                  const int* __restrict__ row_end,
                                                  const int* __restrict__ srcs,
                                                  const ushort16* __restrict__ hb,
                                                  const float* __restrict__ dis,
                                                  const float* __restrict__ bias,
                                                  const int* __restrict__ batch,
                                                  float* __restrict__ u) {
    __shared__ float sp[32][HIDDEN + 1];   // pad 65: write banks differ per g
    __shared__ int gbs[32];
    const int t = threadIdx.x;
    const int lane = t & 63;
    const int wv = t >> 6;
    const int g = lane >> 3;
    const int k = lane & 7;
    const int kb = lane & 56;              // g*8, shfl source base
    const int base = blockIdx.x * 32;
    const int node = base + wv * 8 + g;    // N_NODES = 32*3125 exactly
    const int beg = row_ptr[node];
    const int end = row_end[node];
    const int deg = end - beg;
    const float dn = dis[node];

    int dmax = deg;
    dmax = max(dmax, __shfl_xor(dmax, 8));
    dmax = max(dmax, __shfl_xor(dmax, 16));
    dmax = max(dmax, __shfl_xor(dmax, 32));

    float acc[8];
#pragma unroll
    for (int j = 0; j < 8; ++j) acc[j] = 0.f;

    for (int i0 = 0; i0 < dmax; i0 += 8) {
        // prefetch 8 edges ahead per group (clamped; unconsumed if invalid)
        int idx = beg + i0 + k;
        idx = min(idx, end - 1);
        idx = max(idx, 0);
        const int s8 = srcs[idx];
        const float w8 = dis[s8] * dn;
#pragma unroll
        for (int j = 0; j < 8; ++j) {
            if (i0 + j < deg) {
                const int   si = __shfl(s8, kb | j);
                const float wi = __shfl(w8, kb | j);
                const uint4 v = *(const uint4*)&hb[(size_t)si * HIDDEN + k * 8];
                acc[0] = fmaf(__uint_as_float(v.x << 16),         wi, acc[0]);
                acc[1] = fmaf(__uint_as_float(v.x & 0xffff0000u), wi, acc[1]);
                acc[2] = fmaf(__uint_as_float(v.y << 16),         wi, acc[2]);
                acc[3] = fmaf(__uint_as_float(v.y & 0xffff0000u), wi, acc[3]);
                acc[4] = fmaf(__uint_as_float(v.z << 16),         wi, acc[4]);
                acc[5] = fmaf(__uint_as_float(v.z & 0xffff0000u), wi, acc[5]);
                acc[6] = fmaf(__uint_as_float(v.w << 16),         wi, acc[6]);
                acc[7] = fmaf(__uint_as_float(v.w & 0xffff0000u), wi, acc[7]);
            }
        }
    }

    // self-loop + bias + relu, stage to LDS
    {
        const uint4 hv = *(const uint4*)&hb[(size_t)node * HIDDEN + k * 8];
        const float d2 = dn * dn;
        const float4 b0 = *(const float4*)&bias[k * 8];
        const float4 b1 = *(const float4*)&bias[k * 8 + 4];
        float4 r0, r1;
        r0.x = fmaxf(fmaf(__uint_as_float(hv.x << 16),         d2, acc[0]) + b0.x, 0.f);
        r0.y = fmaxf(fmaf(__uint_as_float(hv.x & 0xffff0000u), d2, acc[1]) + b0.y, 0.f);
        r0.z = fmaxf(fmaf(__uint_as_float(hv.y << 16),         d2, acc[2]) + b0.z, 0.f);
        r0.w = fmaxf(fmaf(__uint_as_float(hv.y & 0xffff0000u), d2, acc[3]) + b0.w, 0.f);
        r1.x = fmaxf(fmaf(__uint_as_float(hv.z << 16),         d2, acc[4]) + b1.x, 0.f);
        r1.y = fmaxf(fmaf(__uint_as_float(hv.z & 0xffff0000u), d2, acc[5]) + b1.y, 0.f);
        r1.z = fmaxf(fmaf(__uint_as_float(hv.w << 16),         d2, acc[6]) + b1.z, 0.f);
        r1.w = fmaxf(fmaf(__uint_as_float(hv.w & 0xffff0000u), d2, acc[7]) + b1.w, 0.f);
        *(float4*)&sp[wv * 8 + g][k * 8]     = r0;
        *(float4*)&sp[wv * 8 + g][k * 8 + 4] = r1;
    }
    if (t < 32) gbs[t] = batch[base + t];
    __syncthreads();

    // pool the 32 staged rows (batch sorted -> few runs)
    if (t < 64) {
        float a = sp[0][t];
        int cg = gbs[0];
        for (int r = 1; r < 32; ++r) {
            const int gr = gbs[r];
            const float vv = sp[r][t];
            if (gr == cg) a += vv;
            else { atomicAdd(&u[cg * HIDDEN + t], a); cg = gr; a = vv; }
        }
        atomicAdd(&u[cg * HIDDEN + t], a);
    }
}

// ---------------------------------------------------------------------------
// K6: out[g] = relu(u[g] @ W1 + b1) @ W2 + b2
// ---------------------------------------------------------------------------
__global__ __launch_bounds__(64) void mlp_kernel(const float* __restrict__ u,
                                                 const float* __restrict__ W1,
                                                 const float* __restrict__ b1,
                                                 const float* __restrict__ W2,
                                                 const float* __restrict__ b2,
                                                 float* __restrict__ out) {
    __shared__ float W1s[HIDDEN * 16];
    __shared__ float W2s[16];
    __shared__ float b1s[16];
    const int t = threadIdx.x;
    for (int i = t; i < HIDDEN * 16; i += 64) W1s[i] = W1[i];
    if (t < 16) { W2s[t] = W2[t]; b1s[t] = b1[t]; }
    __syncthreads();
    if (t < NUM_GRAPHS) {
        float uu[HIDDEN];
#pragma unroll
        for (int k = 0; k < HIDDEN; ++k) uu[k] = u[t * HIDDEN + k];
        float o = b2[0];
#pragma unroll
        for (int j = 0; j < 16; ++j) {
            float s = b1s[j];
#pragma unroll
            for (int k = 0; k < HIDDEN; ++k) s = fmaf(uu[k], W1s[k * 16 + j], s);
            o = fmaf(fmaxf(s, 0.f), W2s[j], o);
        }
        out[t] = o;
    }
}

// ---------------------------------------------------------------------------
extern "C" void kernel_launch(void* const* d_in, const int* in_sizes, int n_in,
                              void* d_out, int out_size, void* d_ws, size_t ws_size,
                              hipStream_t stream) {
    const float* x  = (const float*)d_in[0];
    const float* W  = (const float*)d_in[1];
    const float* b  = (const float*)d_in[2];
    const float* W1 = (const float*)d_in[3];
    const float* b1 = (const float*)d_in[4];
    const float* W2 = (const float*)d_in[5];
    const float* b2 = (const float*)d_in[6];
    const int*   ei = (const int*)d_in[7];     // [2, E] flat
    const int* batch = (const int*)d_in[8];    // [N], sorted
    float* out = (float*)d_out;

    ushort16* hb       = (ushort16*)d_ws;
    int*      src_tmp  = (int*)(hb + (size_t)N_NODES * HIDDEN);
    unsigned char* dst8 = (unsigned char*)(src_tmp + N_EDGES);
    int*      srcs     = (int*)(dst8 + N_EDGES);      // E multiple of 4 -> aligned
    int*      offs     = srcs + N_EDGES;
    int*      row_ptr  = offs + NCHUNK * OFFS_W;
    int*      row_end  = row_ptr + N_NODES;
    float*    dis      = (float*)(row_end + N_NODES);
    int*      bucket_size  = (int*)(dis + N_NODES);
    int*      bucket_start = bucket_size + 512;
    float*    u        = (float*)(bucket_start + 512);

    hipMemsetAsync(bucket_size, 0, 512 * sizeof(int), stream);
    hipMemsetAsync(u, 0, NUM_GRAPHS * HIDDEN * sizeof(float), stream);

    gemm_xw<<<(N_NODES + 63) / 64, 256, 0, stream>>>(x, W, hb);
    partition_kernel<<<NCHUNK, 512, 0, stream>>>(ei, src_tmp, dst8, offs, bucket_size);
    scan_buckets<<<1, 512, 0, stream>>>(bucket_size, bucket_start);
    bucket_csr<<<NBUCKET, 512, 0, stream>>>(offs, src_tmp, dst8, bucket_start,
                                            srcs, row_ptr, row_end, dis);
    agg_kernel<<<N_NODES / 32, 256, 0, stream>>>(row_ptr, row_end, srcs, hb, dis, b, batch, u);
    mlp_kernel<<<1, 64, 0, stream>>>(u, W1, b1, W2, b2, out);
}

// Round 11
// 227.376 us; speedup vs baseline: 1.1825x; 1.0024x over previous
//
#include <hip/hip_runtime.h>

#define N_NODES   100000
#define N_FEAT    128
#define N_EDGES   1600000
#define HIDDEN    64
#define NUM_GRAPHS 64
#define CHUNK   8192
#define NCHUNK  ((N_EDGES + CHUNK - 1) / CHUNK)   // 196
#define BSHIFT  8
#define NBUCKET ((N_NODES + 255) >> 8)            // 391 buckets of 256 nodes
#define OFFS_W  (NBUCKET + 1)                     // 392 entries per chunk
#define XSTRIDE 65                                // u32 stride: bank=(lane+kp)%32 -> 2-way (free)

typedef unsigned int  uint32;
typedef unsigned short ushort16;

// fp32 -> bf16 round-to-nearest-even
static __device__ __forceinline__ unsigned short f2bf(float f) {
    uint32 u = __float_as_uint(f);
    u += 0x7fffu + ((u >> 16) & 1u);
    return (unsigned short)(u >> 16);
}

// ---------------------------------------------------------------------------
// K1: h = x @ W (bf16 staged x, fp32 accumulate, bf16 output). lane = row,
// wave w computes cols [16w,16w+16). x staged in LDS as bf16 pairs (16.6 KB
// -> 9 blocks/CU capacity, whole 1563-block grid resident in one round);
// W via wave-uniform scalar loads.
// ---------------------------------------------------------------------------
__global__ __launch_bounds__(256) void gemm_xw(const float* __restrict__ x,
                                               const float* __restrict__ W,
                                               ushort16* __restrict__ hb) {
    __shared__ uint32 xs[64 * XSTRIDE];        // bf16[64][130], 16.6 KB
    const int tid  = threadIdx.x;
    const int lane = tid & 63;
    const int wid  = __builtin_amdgcn_readfirstlane(tid >> 6);
    const int c0   = wid * 16;
    const int base = blockIdx.x * 64;

    // stage 64 rows x 128 floats -> bf16 pairs (coalesced float4 loads)
#pragma unroll
    for (int j = 0; j < 8; ++j) {
        const int flat = (tid + j * 256) * 4;   // float index in 64x128 tile
        const int r = flat >> 7, k = flat & 127;
        const int row = base + r;
        float4 v = make_float4(0.f, 0.f, 0.f, 0.f);
        if (row < N_NODES) v = *(const float4*)&x[(size_t)row * N_FEAT + k];
        xs[r * XSTRIDE + (k >> 1)]     = (uint32)f2bf(v.x) | ((uint32)f2bf(v.y) << 16);
        xs[r * XSTRIDE + (k >> 1) + 1] = (uint32)f2bf(v.z) | ((uint32)f2bf(v.w) << 16);
    }
    __syncthreads();

    float acc[16];
#pragma unroll
    for (int c = 0; c < 16; ++c) acc[c] = 0.f;

    const float* __restrict__ Wp = W + c0;     // wave-uniform pointer
#pragma unroll 4
    for (int kp = 0; kp < 64; ++kp) {          // k processed in bf16 pairs
        const uint32 u = xs[lane * XSTRIDE + kp];
        const float x0 = __uint_as_float(u << 16);
        const float x1 = __uint_as_float(u & 0xffff0000u);
        const int k0 = kp * 2;
#pragma unroll
        for (int c = 0; c < 16; ++c)
            acc[c] = fmaf(x0, Wp[k0 * HIDDEN + c], acc[c]);
#pragma unroll
        for (int c = 0; c < 16; ++c)
            acc[c] = fmaf(x1, Wp[(k0 + 1) * HIDDEN + c], acc[c]);
    }

    const int row = base + lane;
    if (row < N_NODES) {
        ushort16* hp = &hb[(size_t)row * HIDDEN + c0];
        uint32 o[8];
#pragma unroll
        for (int c = 0; c < 16; c += 2)
            o[c >> 1] = (uint32)f2bf(acc[c]) | ((uint32)f2bf(acc[c + 1]) << 16);
        *(uint4*)&hp[0] = make_uint4(o[0], o[1], o[2], o[3]);
        *(uint4*)&hp[8] = make_uint4(o[4], o[5], o[6], o[7]);
    }
}

// ---------------------------------------------------------------------------
// K2: partition edges into 391 dst-buckets per 8192-edge chunk via LDS; all
// global writes coalesced. dst stored as uint8 in-bucket id. Accumulates
// bucket sizes (bucket_size pre-zeroed).
// ---------------------------------------------------------------------------
__global__ __launch_bounds__(512) void partition_kernel(const int* __restrict__ ei,
                                                        int* __restrict__ src_out,
                                                        unsigned char* __restrict__ dst8,
                                                        int* __restrict__ offs,
                                                        int* __restrict__ bucket_size) {
    __shared__ int hist[512];
    __shared__ int excl[512];
    __shared__ int ssrc[CHUNK];     // 32 KB
    __shared__ int sdst[CHUNK];     // 32 KB
    const int c = blockIdx.x;
    const int base = c * CHUNK;
    const int n = min(CHUNK, N_EDGES - base);   // always a multiple of 4
    const int t = threadIdx.x;
    hist[t] = 0;
    __syncthreads();

    int es[CHUNK / 512], ed[CHUNK / 512], rk[CHUNK / 512];
#pragma unroll
    for (int k = 0; k < CHUNK / 512; ++k) {
        const int i = t + k * 512;
        if (i < n) {
            ed[k] = __builtin_nontemporal_load(&ei[N_EDGES + base + i]);
            es[k] = __builtin_nontemporal_load(&ei[base + i]);
            rk[k] = atomicAdd(&hist[ed[k] >> BSHIFT], 1);
        }
    }
    __syncthreads();

    const int cnt = hist[t];
    for (int off = 1; off < 512; off <<= 1) {
        const int v = (t >= off) ? hist[t - off] : 0;
        __syncthreads();
        hist[t] += v;
        __syncthreads();
    }
    excl[t] = hist[t] - cnt;
    __syncthreads();
    if (t <= NBUCKET) offs[c * OFFS_W + t] = base + excl[t];   // excl[NBUCKET]==n
    if (t < NBUCKET && cnt > 0) atomicAdd(&bucket_size[t], cnt);

#pragma unroll
    for (int k = 0; k < CHUNK / 512; ++k) {
        const int i = t + k * 512;
        if (i < n) {
            const int pos = excl[ed[k] >> BSHIFT] + rk[k];
            ssrc[pos] = es[k];
            sdst[pos] = ed[k];
        }
    }
    __syncthreads();

    for (int i = t; i < n; i += 512)
        src_out[base + i] = ssrc[i];
    for (int i = t * 4; i < n; i += 2048) {
        const uint32 p = (uint32)(sdst[i] & 255)
                       | ((uint32)(sdst[i + 1] & 255) << 8)
                       | ((uint32)(sdst[i + 2] & 255) << 16)
                       | ((uint32)(sdst[i + 3] & 255) << 24);
        *(uint32*)&dst8[base + i] = p;
    }
}

// ---------------------------------------------------------------------------
// K3: exclusive scan of bucket_size -> bucket_start (1 block).
// ---------------------------------------------------------------------------
__global__ __launch_bounds__(512) void scan_buckets(const int* __restrict__ bucket_size,
                                                    int* __restrict__ bucket_start) {
    __shared__ int s[512];
    const int t = threadIdx.x;
    const int v = (t < NBUCKET) ? bucket_size[t] : 0;
    s[t] = v;
    __syncthreads();
    for (int off = 1; off < 512; off <<= 1) {
        const int a = (t >= off) ? s[t - off] : 0;
        __syncthreads();
        s[t] += a;
        __syncthreads();
    }
    if (t < NBUCKET) bucket_start[t] = s[t] - v;
}

// ---------------------------------------------------------------------------
// K4: per-bucket CSR finalize (pass1 hist -> row_ptr/row_end/dis; pass2
// scatter src into the block-private window, combining in the owning CU's L2).
// ---------------------------------------------------------------------------
__global__ __launch_bounds__(512) void bucket_csr(const int* __restrict__ offs,
                                                  const int* __restrict__ src_tmp,
                                                  const unsigned char* __restrict__ dst8,
                                                  const int* __restrict__ bucket_start,
                                                  int* __restrict__ srcs,
                                                  int* __restrict__ row_ptr,
                                                  int* __restrict__ row_end,
                                                  float* __restrict__ dis) {
    __shared__ int hist[256];
    __shared__ int nxt[256];
    __shared__ int segb[NCHUNK], sege[NCHUNK];
    const int b = blockIdx.x;
    const int lo = b << BSHIFT;
    const int t = threadIdx.x;
    const int lane = t & 63;
    const int wv = t >> 6;                      // 8 waves
    const int bstart = bucket_start[b];

    if (t < 256) hist[t] = 0;
    for (int c = t; c < NCHUNK; c += 512) {
        segb[c] = offs[c * OFFS_W + b];
        sege[c] = offs[c * OFFS_W + b + 1];
    }
    __syncthreads();

    for (int c = wv; c < NCHUNK; c += 8)
        for (int i = segb[c] + lane; i < sege[c]; i += 64)
            atomicAdd(&hist[dst8[i]], 1);
    __syncthreads();

    const int cnt = (t < 256) ? hist[t] : 0;
    for (int off = 1; off < 256; off <<= 1) {
        int v = 0;
        if (t < 256 && t >= off) v = hist[t - off];
        __syncthreads();
        if (t < 256) hist[t] += v;
        __syncthreads();
    }
    if (t < 256) {
        const int excl = hist[t] - cnt;
        nxt[t] = excl;
        const int node = lo + t;
        if (node < N_NODES) {
            row_ptr[node] = bstart + excl;
            row_end[node] = bstart + excl + cnt;
            dis[node]     = rsqrtf((float)cnt + 1.0f);
        }
    }
    __syncthreads();

    for (int c = wv; c < NCHUNK; c += 8)
        for (int i = segb[c] + lane; i < sege[c]; i += 64) {
            const int d = dst8[i];
            const int s = src_tmp[i];
            const int pos = atomicAdd(&nxt[d], 1);
            srcs[bstart + pos] = s;
        }
}

// ---------------------------------------------------------------------------
// K5: gather-aggregate, 8 nodes per wave for MLP. Lane group g (8 lanes) owns
// node 32*blk+8*wv+g; lane k owns cols [8k,8k+8) (uint4 of bf16). One edge
// per node per iteration -> trip count ~deg of independent 16-line gathers.
// No cross-lane reduction. Epilogue stages 32 rows in LDS and pools with
// ~1 atomic burst per block (batch sorted).
// ---------------------------------------------------------------------------
__global__ __launch_bounds__(256) void agg_kernel(const int* __restrict__ row_ptr,
                                                  const int* __restrict__ row_end,
                                                  const int* __restrict__ srcs,
                                                  const ushort16* __restrict__ hb,
                                                  const float* __restrict__ dis,
                                                  const float* __restrict__ bias,
                                                  const int* __restrict__ batch,
                                                  float* __restrict__ u) {
    __shared__ float sp[32][HIDDEN + 1];   // pad 65: write banks differ per g
    __shared__ int gbs[32];
    const int t = threadIdx.x;
    const int lane = t & 63;
    const int wv = t >> 6;
    const int g = lane >> 3;
    const int k = lane & 7;
    const int kb = lane & 56;              // g*8, shfl source base
    const int base = blockIdx.x * 32;
    const int node = base + wv * 8 + g;    // N_NODES = 32*3125 exactly
    const int beg = row_ptr[node];
    const int end = row_end[node];
    const int deg = end - beg;
    const float dn = dis[node];

    int dmax = deg;
    dmax = max(dmax, __shfl_xor(dmax, 8));
    dmax = max(dmax, __shfl_xor(dmax, 16));
    dmax = max(dmax, __shfl_xor(dmax, 32));

    float acc[8];
#pragma unroll
    for (int j = 0; j < 8; ++j) acc[j] = 0.f;

    for (int i0 = 0; i0 < dmax; i0 += 8) {
        // prefetch 8 edges ahead per group (clamped; unconsumed if invalid)
        int idx = beg + i0 + k;
        idx = min(idx, end - 1);
        idx = max(idx, 0);
        const int s8 = srcs[idx];
        const float w8 = dis[s8] * dn;
#pragma unroll
        for (int j = 0; j < 8; ++j) {
            if (i0 + j < deg) {
                const int   si = __shfl(s8, kb | j);
                const float wi = __shfl(w8, kb | j);
                const uint4 v = *(const uint4*)&hb[(size_t)si * HIDDEN + k * 8];
                acc[0] = fmaf(__uint_as_float(v.x << 16),         wi, acc[0]);
                acc[1] = fmaf(__uint_as_float(v.x & 0xffff0000u), wi, acc[1]);
                acc[2] = fmaf(__uint_as_float(v.y << 16),         wi, acc[2]);
                acc[3] = fmaf(__uint_as_float(v.y & 0xffff0000u), wi, acc[3]);
                acc[4] = fmaf(__uint_as_float(v.z << 16),         wi, acc[4]);
                acc[5] = fmaf(__uint_as_float(v.z & 0xffff0000u), wi, acc[5]);
                acc[6] = fmaf(__uint_as_float(v.w << 16),         wi, acc[6]);
                acc[7] = fmaf(__uint_as_float(v.w & 0xffff0000u), wi, acc[7]);
            }
        }
    }

    // self-loop + bias + relu, stage to LDS
    {
        const uint4 hv = *(const uint4*)&hb[(size_t)node * HIDDEN + k * 8];
        const float d2 = dn * dn;
        const float4 b0 = *(const float4*)&bias[k * 8];
        const float4 b1 = *(const float4*)&bias[k * 8 + 4];
        float4 r0, r1;
        r0.x = fmaxf(fmaf(__uint_as_float(hv.x << 16),         d2, acc[0]) + b0.x, 0.f);
        r0.y = fmaxf(fmaf(__uint_as_float(hv.x & 0xffff0000u), d2, acc[1]) + b0.y, 0.f);
        r0.z = fmaxf(fmaf(__uint_as_float(hv.y << 16),         d2, acc[2]) + b0.z, 0.f);
        r0.w = fmaxf(fmaf(__uint_as_float(hv.y & 0xffff0000u), d2, acc[3]) + b0.w, 0.f);
        r1.x = fmaxf(fmaf(__uint_as_float(hv.z << 16),         d2, acc[4]) + b1.x, 0.f);
        r1.y = fmaxf(fmaf(__uint_as_float(hv.z & 0xffff0000u), d2, acc[5]) + b1.y, 0.f);
        r1.z = fmaxf(fmaf(__uint_as_float(hv.w << 16),         d2, acc[6]) + b1.z, 0.f);
        r1.w = fmaxf(fmaf(__uint_as_float(hv.w & 0xffff0000u), d2, acc[7]) + b1.w, 0.f);
        *(float4*)&sp[wv * 8 + g][k * 8]     = r0;
        *(float4*)&sp[wv * 8 + g][k * 8 + 4] = r1;
    }
    if (t < 32) gbs[t] = batch[base + t];
    __syncthreads();

    // pool the 32 staged rows (batch sorted -> few runs)
    if (t < 64) {
        float a = sp[0][t];
        int cg = gbs[0];
        for (int r = 1; r < 32; ++r) {
            const int gr = gbs[r];
            const float vv = sp[r][t];
            if (gr == cg) a += vv;
            else { atomicAdd(&u[cg * HIDDEN + t], a); cg = gr; a = vv; }
        }
        atomicAdd(&u[cg * HIDDEN + t], a);
    }
}

// ---------------------------------------------------------------------------
// K6: out[g] = relu(u[g] @ W1 + b1) @ W2 + b2
// ---------------------------------------------------------------------------
__global__ __launch_bounds__(64) void mlp_kernel(const float* __restrict__ u,
                                                 const float* __restrict__ W1,
                                                 const float* __restrict__ b1,
                                                 const float* __restrict__ W2,
                                                 const float* __restrict__ b2,
                                                 float* __restrict__ out) {
    __shared__ float W1s[HIDDEN * 16];
    __shared__ float W2s[16];
    __shared__ float b1s[16];
    const int t = threadIdx.x;
    for (int i = t; i < HIDDEN * 16; i += 64) W1s[i] = W1[i];
    if (t < 16) { W2s[t] = W2[t]; b1s[t] = b1[t]; }
    __syncthreads();
    if (t < NUM_GRAPHS) {
        float uu[HIDDEN];
#pragma unroll
        for (int k = 0; k < HIDDEN; ++k) uu[k] = u[t * HIDDEN + k];
        float o = b2[0];
#pragma unroll
        for (int j = 0; j < 16; ++j) {
            float s = b1s[j];
#pragma unroll
            for (int k = 0; k < HIDDEN; ++k) s = fmaf(uu[k], W1s[k * 16 + j], s);
            o = fmaf(fmaxf(s, 0.f), W2s[j], o);
        }
        out[t] = o;
    }
}

// ---------------------------------------------------------------------------
extern "C" void kernel_launch(void* const* d_in, const int* in_sizes, int n_in,
                              void* d_out, int out_size, void* d_ws, size_t ws_size,
                              hipStream_t stream) {
    const float* x  = (const float*)d_in[0];
    const float* W  = (const float*)d_in[1];
    const float* b  = (const float*)d_in[2];
    const float* W1 = (const float*)d_in[3];
    const float* b1 = (const float*)d_in[4];
    const float* W2 = (const float*)d_in[5];
    const float* b2 = (const float*)d_in[6];
    const int*   ei = (const int*)d_in[7];     // [2, E] flat
    const int* batch = (const int*)d_in[8];    // [N], sorted
    float* out = (float*)d_out;

    ushort16* hb       = (ushort16*)d_ws;
    int*      src_tmp  = (int*)(hb + (size_t)N_NODES * HIDDEN);
    unsigned char* dst8 = (unsigned char*)(src_tmp + N_EDGES);
    int*      srcs     = (int*)(dst8 + N_EDGES);      // E multiple of 4 -> aligned
    int*      offs     = srcs + N_EDGES;
    int*      row_ptr  = offs + NCHUNK * OFFS_W;
    int*      row_end  = row_ptr + N_NODES;
    float*    dis      = (float*)(row_end + N_NODES);
    int*      bucket_size  = (int*)(dis + N_NODES);
    int*      bucket_start = bucket_size + 512;
    float*    u        = (float*)(bucket_start + 512);

    hipMemsetAsync(bucket_size, 0, 512 * sizeof(int), stream);
    hipMemsetAsync(u, 0, NUM_GRAPHS * HIDDEN * sizeof(float), stream);

    gemm_xw<<<(N_NODES + 63) / 64, 256, 0, stream>>>(x, W, hb);
    partition_kernel<<<NCHUNK, 512, 0, stream>>>(ei, src_tmp, dst8, offs, bucket_size);
    scan_buckets<<<1, 512, 0, stream>>>(bucket_size, bucket_start);
    bucket_csr<<<NBUCKET, 512, 0, stream>>>(offs, src_tmp, dst8, bucket_start,
                                            srcs, row_ptr, row_end, dis);
    agg_kernel<<<N_NODES / 32, 256, 0, stream>>>(row_ptr, row_end, srcs, hb, dis, b, batch, u);
    mlp_kernel<<<1, 64, 0, stream>>>(u, W1, b1, W2, b2, out);
}

// Round 12
// 214.443 us; speedup vs baseline: 1.2538x; 1.0603x over previous
//
#include <hip/hip_runtime.h>

#define N_NODES   100000
#define N_FEAT    128
#define N_EDGES   1600000
#define HIDDEN    64
#define NUM_GRAPHS 64
#define CHUNK   8192
#define NCHUNK  ((N_EDGES + CHUNK - 1) / CHUNK)   // 196
#define BSHIFT  8
#define NBUCKET ((N_NODES + 255) >> 8)            // 391 buckets of 256 nodes
#define OFFS_W  (NBUCKET + 1)                     // 392 entries per chunk

typedef unsigned int  uint32;
typedef unsigned short ushort16;

typedef __attribute__((ext_vector_type(8))) __bf16 bf16x8;
typedef __attribute__((ext_vector_type(4))) float  f32x4;
union Frag8 { bf16x8 v; unsigned short s[8]; uint4 q; };

// fp32 -> bf16 round-to-nearest-even
static __device__ __forceinline__ unsigned short f2bf(float f) {
    uint32 u = __float_as_uint(f);
    u += 0x7fffu + ((u >> 16) & 1u);
    return (unsigned short)(u >> 16);
}

// ---------------------------------------------------------------------------
// K0: Wt[n][k] = bf16(W[k][n])  (16 KB, built once; gemm B-frags read it)
// ---------------------------------------------------------------------------
__global__ __launch_bounds__(256) void w_transpose(const float* __restrict__ W,
                                                   ushort16* __restrict__ Wt) {
    const int base = blockIdx.x * 1024 + threadIdx.x;
#pragma unroll
    for (int j = 0; j < 4; ++j) {
        const int idx = base + j * 256;
        const int k = idx >> 6, n = idx & 63;
        Wt[n * N_FEAT + k] = f2bf(W[idx]);
    }
}

// ---------------------------------------------------------------------------
// K1: h = x @ W via MFMA (bf16 in, fp32 acc, bf16 out). No LDS, no barriers.
// Wave computes a 16-row x 64-col slab: 4 n-tiles x 4 k-chunks of
// mfma_f32_16x16x32_bf16. A loaded from x (fp32->bf16 in-reg), B from Wt
// (L1-hot 16 KB). Layouts (guide-verified): A[m=lane&15][k=quad*8+j],
// B[k=quad*8+j][n=lane&15], D col=lane&15 row=quad*4+reg.
// ---------------------------------------------------------------------------
__global__ __launch_bounds__(256) void gemm_xw(const float* __restrict__ x,
                                               const ushort16* __restrict__ Wt,
                                               ushort16* __restrict__ hb) {
    const int lane = threadIdx.x & 63;
    const int wv   = threadIdx.x >> 6;
    const int m15  = lane & 15;
    const int quad = lane >> 4;
    const int base = blockIdx.x * 64 + wv * 16;          // 16 rows per wave
    const int arow = min(base + m15, N_NODES - 1);       // clamp tail (stores guarded)

    // A source: x[arow][kc*32 + quad*8 .. +7], 4 chunks x 2 float4
    const float* xr = &x[(size_t)arow * N_FEAT + quad * 8];
    float4 xa[4][2];
#pragma unroll
    for (int kc = 0; kc < 4; ++kc) {
        xa[kc][0] = *(const float4*)&xr[kc * 32];
        xa[kc][1] = *(const float4*)&xr[kc * 32 + 4];
    }

    // B frags: Wt[nt*16+m15][kc*32 + quad*8 .. +7]
    Frag8 bf[4][4];
#pragma unroll
    for (int nt = 0; nt < 4; ++nt) {
        const ushort16* wr = &Wt[(nt * 16 + m15) * N_FEAT + quad * 8];
#pragma unroll
        for (int kc = 0; kc < 4; ++kc)
            bf[nt][kc].q = *(const uint4*)&wr[kc * 32];
    }

    // convert A to bf16 frags
    Frag8 af[4];
#pragma unroll
    for (int kc = 0; kc < 4; ++kc) {
        const float* f = (const float*)&xa[kc][0];
#pragma unroll
        for (int j = 0; j < 8; ++j) af[kc].s[j] = f2bf(f[j]);
    }

    f32x4 acc[4];
#pragma unroll
    for (int nt = 0; nt < 4; ++nt) acc[nt] = (f32x4){0.f, 0.f, 0.f, 0.f};

#pragma unroll
    for (int kc = 0; kc < 4; ++kc)
#pragma unroll
        for (int nt = 0; nt < 4; ++nt)
            acc[nt] = __builtin_amdgcn_mfma_f32_16x16x32_bf16(af[kc].v, bf[nt][kc].v,
                                                              acc[nt], 0, 0, 0);

    // D: row = base + quad*4 + r, col = nt*16 + m15
#pragma unroll
    for (int r = 0; r < 4; ++r) {
        const int orow = base + quad * 4 + r;
        if (orow < N_NODES) {
#pragma unroll
            for (int nt = 0; nt < 4; ++nt)
                hb[(size_t)orow * HIDDEN + nt * 16 + m15] = f2bf(acc[nt][r]);
        }
    }
}

// ---------------------------------------------------------------------------
// K2: partition edges into 391 dst-buckets per 8192-edge chunk via LDS; all
// global writes coalesced. dst stored as uint8 in-bucket id. Accumulates
// bucket sizes (bucket_size pre-zeroed).
// ---------------------------------------------------------------------------
__global__ __launch_bounds__(512) void partition_kernel(const int* __restrict__ ei,
                                                        int* __restrict__ src_out,
                                                        unsigned char* __restrict__ dst8,
                                                        int* __restrict__ offs,
                                                        int* __restrict__ bucket_size) {
    __shared__ int hist[512];
    __shared__ int excl[512];
    __shared__ int ssrc[CHUNK];     // 32 KB
    __shared__ int sdst[CHUNK];     // 32 KB
    const int c = blockIdx.x;
    const int base = c * CHUNK;
    const int n = min(CHUNK, N_EDGES - base);   // always a multiple of 4
    const int t = threadIdx.x;
    hist[t] = 0;
    __syncthreads();

    int es[CHUNK / 512], ed[CHUNK / 512], rk[CHUNK / 512];
#pragma unroll
    for (int k = 0; k < CHUNK / 512; ++k) {
        const int i = t + k * 512;
        if (i < n) {
            ed[k] = __builtin_nontemporal_load(&ei[N_EDGES + base + i]);
            es[k] = __builtin_nontemporal_load(&ei[base + i]);
            rk[k] = atomicAdd(&hist[ed[k] >> BSHIFT], 1);
        }
    }
    __syncthreads();

    const int cnt = hist[t];
    for (int off = 1; off < 512; off <<= 1) {
        const int v = (t >= off) ? hist[t - off] : 0;
        __syncthreads();
        hist[t] += v;
        __syncthreads();
    }
    excl[t] = hist[t] - cnt;
    __syncthreads();
    if (t <= NBUCKET) offs[c * OFFS_W + t] = base + excl[t];   // excl[NBUCKET]==n
    if (t < NBUCKET && cnt > 0) atomicAdd(&bucket_size[t], cnt);

#pragma unroll
    for (int k = 0; k < CHUNK / 512; ++k) {
        const int i = t + k * 512;
        if (i < n) {
            const int pos = excl[ed[k] >> BSHIFT] + rk[k];
            ssrc[pos] = es[k];
            sdst[pos] = ed[k];
        }
    }
    __syncthreads();

    for (int i = t; i < n; i += 512)
        src_out[base + i] = ssrc[i];
    for (int i = t * 4; i < n; i += 2048) {
        const uint32 p = (uint32)(sdst[i] & 255)
                       | ((uint32)(sdst[i + 1] & 255) << 8)
                       | ((uint32)(sdst[i + 2] & 255) << 16)
                       | ((uint32)(sdst[i + 3] & 255) << 24);
        *(uint32*)&dst8[base + i] = p;
    }
}

// ---------------------------------------------------------------------------
// K3: exclusive scan of bucket_size -> bucket_start (1 block).
// ---------------------------------------------------------------------------
__global__ __launch_bounds__(512) void scan_buckets(const int* __restrict__ bucket_size,
                                                    int* __restrict__ bucket_start) {
    __shared__ int s[512];
    const int t = threadIdx.x;
    const int v = (t < NBUCKET) ? bucket_size[t] : 0;
    s[t] = v;
    __syncthreads();
    for (int off = 1; off < 512; off <<= 1) {
        const int a = (t >= off) ? s[t - off] : 0;
        __syncthreads();
        s[t] += a;
        __syncthreads();
    }
    if (t < NBUCKET) bucket_start[t] = s[t] - v;
}

// ---------------------------------------------------------------------------
// K4: per-bucket CSR finalize (pass1 hist -> row_ptr/row_end/dis; pass2
// scatter src into the block-private window, combining in the owning CU's L2).
// ---------------------------------------------------------------------------
__global__ __launch_bounds__(512) void bucket_csr(const int* __restrict__ offs,
                                                  const int* __restrict__ src_tmp,
                                                  const unsigned char* __restrict__ dst8,
                                                  const int* __restrict__ bucket_start,
                                                  int* __restrict__ srcs,
                                                  int* __restrict__ row_ptr,
                                                  int* __restrict__ row_end,
                                                  float* __restrict__ dis) {
    __shared__ int hist[256];
    __shared__ int nxt[256];
    __shared__ int segb[NCHUNK], sege[NCHUNK];
    const int b = blockIdx.x;
    const int lo = b << BSHIFT;
    const int t = threadIdx.x;
    const int lane = t & 63;
    const int wv = t >> 6;                      // 8 waves
    const int bstart = bucket_start[b];

    if (t < 256) hist[t] = 0;
    for (int c = t; c < NCHUNK; c += 512) {
        segb[c] = offs[c * OFFS_W + b];
        sege[c] = offs[c * OFFS_W + b + 1];
    }
    __syncthreads();

    for (int c = wv; c < NCHUNK; c += 8)
        for (int i = segb[c] + lane; i < sege[c]; i += 64)
            atomicAdd(&hist[dst8[i]], 1);
    __syncthreads();

    const int cnt = (t < 256) ? hist[t] : 0;
    for (int off = 1; off < 256; off <<= 1) {
        int v = 0;
        if (t < 256 && t >= off) v = hist[t - off];
        __syncthreads();
        if (t < 256) hist[t] += v;
        __syncthreads();
    }
    if (t < 256) {
        const int excl = hist[t] - cnt;
        nxt[t] = excl;
        const int node = lo + t;
        if (node < N_NODES) {
            row_ptr[node] = bstart + excl;
            row_end[node] = bstart + excl + cnt;
            dis[node]     = rsqrtf((float)cnt + 1.0f);
        }
    }
    __syncthreads();

    for (int c = wv; c < NCHUNK; c += 8)
        for (int i = segb[c] + lane; i < sege[c]; i += 64) {
            const int d = dst8[i];
            const int s = src_tmp[i];
            const int pos = atomicAdd(&nxt[d], 1);
            srcs[bstart + pos] = s;
        }
}

// ---------------------------------------------------------------------------
// K5: gather-aggregate, 8 nodes per wave for MLP. Lane group g (8 lanes) owns
// node 32*blk+8*wv+g; lane k owns cols [8k,8k+8) (uint4 of bf16). One edge
// per node per iteration -> trip count ~deg of independent 16-line gathers.
// No cross-lane reduction. Epilogue stages 32 rows in LDS and pools with
// ~1 atomic burst per block (batch sorted).
// ---------------------------------------------------------------------------
__global__ __launch_bounds__(256) void agg_kernel(const int* __restrict__ row_ptr,
                                                  const int* __restrict__ row_end,
                                                  const int* __restrict__ srcs,
                                                  const ushort16* __restrict__ hb,
                                                  const float* __restrict__ dis,
                                                  const float* __restrict__ bias,
                                                  const int* __restrict__ batch,
                                                  float* __restrict__ u) {
    __shared__ float sp[32][HIDDEN + 1];   // pad 65: write banks differ per g
    __shared__ int gbs[32];
    const int t = threadIdx.x;
    const int lane = t & 63;
    const int wv = t >> 6;
    const int g = lane >> 3;
    const int k = lane & 7;
    const int kb = lane & 56;              // g*8, shfl source base
    const int base = blockIdx.x * 32;
    const int node = base + wv * 8 + g;    // N_NODES = 32*3125 exactly
    const int beg = row_ptr[node];
    const int end = row_end[node];
    const int deg = end - beg;
    const float dn = dis[node];

    int dmax = deg;
    dmax = max(dmax, __shfl_xor(dmax, 8));
    dmax = max(dmax, __shfl_xor(dmax, 16));
    dmax = max(dmax, __shfl_xor(dmax, 32));

    float acc[8];
#pragma unroll
    for (int j = 0; j < 8; ++j) acc[j] = 0.f;

    for (int i0 = 0; i0 < dmax; i0 += 8) {
        // prefetch 8 edges ahead per group (clamped; unconsumed if invalid)
        int idx = beg + i0 + k;
        idx = min(idx, end - 1);
        idx = max(idx, 0);
        const int s8 = srcs[idx];
        const float w8 = dis[s8] * dn;
#pragma unroll
        for (int j = 0; j < 8; ++j) {
            if (i0 + j < deg) {
                const int   si = __shfl(s8, kb | j);
                const float wi = __shfl(w8, kb | j);
                const uint4 v = *(const uint4*)&hb[(size_t)si * HIDDEN + k * 8];
                acc[0] = fmaf(__uint_as_float(v.x << 16),         wi, acc[0]);
                acc[1] = fmaf(__uint_as_float(v.x & 0xffff0000u), wi, acc[1]);
                acc[2] = fmaf(__uint_as_float(v.y << 16),         wi, acc[2]);
                acc[3] = fmaf(__uint_as_float(v.y & 0xffff0000u), wi, acc[3]);
                acc[4] = fmaf(__uint_as_float(v.z << 16),         wi, acc[4]);
                acc[5] = fmaf(__uint_as_float(v.z & 0xffff0000u), wi, acc[5]);
                acc[6] = fmaf(__uint_as_float(v.w << 16),         wi, acc[6]);
                acc[7] = fmaf(__uint_as_float(v.w & 0xffff0000u), wi, acc[7]);
            }
        }
    }

    // self-loop + bias + relu, stage to LDS
    {
        const uint4 hv = *(const uint4*)&hb[(size_t)node * HIDDEN + k * 8];
        const float d2 = dn * dn;
        const float4 b0 = *(const float4*)&bias[k * 8];
        const float4 b1 = *(const float4*)&bias[k * 8 + 4];
        float4 r0, r1;
        r0.x = fmaxf(fmaf(__uint_as_float(hv.x << 16),         d2, acc[0]) + b0.x, 0.f);
        r0.y = fmaxf(fmaf(__uint_as_float(hv.x & 0xffff0000u), d2, acc[1]) + b0.y, 0.f);
        r0.z = fmaxf(fmaf(__uint_as_float(hv.y << 16),         d2, acc[2]) + b0.z, 0.f);
        r0.w = fmaxf(fmaf(__uint_as_float(hv.y & 0xffff0000u), d2, acc[3]) + b0.w, 0.f);
        r1.x = fmaxf(fmaf(__uint_as_float(hv.z << 16),         d2, acc[4]) + b1.x, 0.f);
        r1.y = fmaxf(fmaf(__uint_as_float(hv.z & 0xffff0000u), d2, acc[5]) + b1.y, 0.f);
        r1.z = fmaxf(fmaf(__uint_as_float(hv.w << 16),         d2, acc[6]) + b1.z, 0.f);
        r1.w = fmaxf(fmaf(__uint_as_float(hv.w & 0xffff0000u), d2, acc[7]) + b1.w, 0.f);
        *(float4*)&sp[wv * 8 + g][k * 8]     = r0;
        *(float4*)&sp[wv * 8 + g][k * 8 + 4] = r1;
    }
    if (t < 32) gbs[t] = batch[base + t];
    __syncthreads();

    // pool the 32 staged rows (batch sorted -> few runs)
    if (t < 64) {
        float a = sp[0][t];
        int cg = gbs[0];
        for (int r = 1; r < 32; ++r) {
            const int gr = gbs[r];
            const float vv = sp[r][t];
            if (gr == cg) a += vv;
            else { atomicAdd(&u[cg * HIDDEN + t], a); cg = gr; a = vv; }
        }
        atomicAdd(&u[cg * HIDDEN + t], a);
    }
}

// ---------------------------------------------------------------------------
// K6: out[g] = relu(u[g] @ W1 + b1) @ W2 + b2
// ---------------------------------------------------------------------------
__global__ __launch_bounds__(64) void mlp_kernel(const float* __restrict__ u,
                                                 const float* __restrict__ W1,
                                                 const float* __restrict__ b1,
                                                 const float* __restrict__ W2,
                                                 const float* __restrict__ b2,
                                                 float* __restrict__ out) {
    __shared__ float W1s[HIDDEN * 16];
    __shared__ float W2s[16];
    __shared__ float b1s[16];
    const int t = threadIdx.x;
    for (int i = t; i < HIDDEN * 16; i += 64) W1s[i] = W1[i];
    if (t < 16) { W2s[t] = W2[t]; b1s[t] = b1[t]; }
    __syncthreads();
    if (t < NUM_GRAPHS) {
        float uu[HIDDEN];
#pragma unroll
        for (int k = 0; k < HIDDEN; ++k) uu[k] = u[t * HIDDEN + k];
        float o = b2[0];
#pragma unroll
        for (int j = 0; j < 16; ++j) {
            float s = b1s[j];
#pragma unroll
            for (int k = 0; k < HIDDEN; ++k) s = fmaf(uu[k], W1s[k * 16 + j], s);
            o = fmaf(fmaxf(s, 0.f), W2s[j], o);
        }
        out[t] = o;
    }
}

// ---------------------------------------------------------------------------
extern "C" void kernel_launch(void* const* d_in, const int* in_sizes, int n_in,
                              void* d_out, int out_size, void* d_ws, size_t ws_size,
                              hipStream_t stream) {
    const float* x  = (const float*)d_in[0];
    const float* W  = (const float*)d_in[1];
    const float* b  = (const float*)d_in[2];
    const float* W1 = (const float*)d_in[3];
    const float* b1 = (const float*)d_in[4];
    const float* W2 = (const float*)d_in[5];
    const float* b2 = (const float*)d_in[6];
    const int*   ei = (const int*)d_in[7];     // [2, E] flat
    const int* batch = (const int*)d_in[8];    // [N], sorted
    float* out = (float*)d_out;

    ushort16* hb       = (ushort16*)d_ws;
    int*      src_tmp  = (int*)(hb + (size_t)N_NODES * HIDDEN);
    unsigned char* dst8 = (unsigned char*)(src_tmp + N_EDGES);
    int*      srcs     = (int*)(dst8 + N_EDGES);      // E multiple of 4 -> aligned
    int*      offs     = srcs + N_EDGES;
    int*      row_ptr  = offs + NCHUNK * OFFS_W;
    int*      row_end  = row_ptr + N_NODES;
    float*    dis      = (float*)(row_end + N_NODES);
    int*      bucket_size  = (int*)(dis + N_NODES);
    int*      bucket_start = bucket_size + 512;
    float*    u        = (float*)(bucket_start + 512);
    ushort16* Wtg      = (ushort16*)(u + NUM_GRAPHS * HIDDEN);   // 64x128 bf16

    hipMemsetAsync(bucket_size, 0, 512 * sizeof(int), stream);
    hipMemsetAsync(u, 0, NUM_GRAPHS * HIDDEN * sizeof(float), stream);

    w_transpose<<<8, 256, 0, stream>>>(W, Wtg);
    gemm_xw<<<(N_NODES + 63) / 64, 256, 0, stream>>>(x, Wtg, hb);
    partition_kernel<<<NCHUNK, 512, 0, stream>>>(ei, src_tmp, dst8, offs, bucket_size);
    scan_buckets<<<1, 512, 0, stream>>>(bucket_size, bucket_start);
    bucket_csr<<<NBUCKET, 512, 0, stream>>>(offs, src_tmp, dst8, bucket_start,
                                            srcs, row_ptr, row_end, dis);
    agg_kernel<<<N_NODES / 32, 256, 0, stream>>>(row_ptr, row_end, srcs, hb, dis, b, batch, u);
    mlp_kernel<<<1, 64, 0, stream>>>(u, W1, b1, W2, b2, out);
}

// Round 13
// 205.813 us; speedup vs baseline: 1.3063x; 1.0419x over previous
//
#include <hip/hip_runtime.h>

#define N_NODES   100000
#define N_FEAT    128
#define N_EDGES   1600000
#define HIDDEN    64
#define NUM_GRAPHS 64
#define CHUNK   8192
#define NCHUNK  ((N_EDGES + CHUNK - 1) / CHUNK)   // 196
#define BSHIFT  8
#define NBUCKET ((N_NODES + 255) >> 8)            // 391 buckets of 256 nodes
#define OFFS_W  (NBUCKET + 1)                     // 392 entries per chunk

typedef unsigned int  uint32;
typedef unsigned short ushort16;

typedef __attribute__((ext_vector_type(8))) __bf16 bf16x8;
typedef __attribute__((ext_vector_type(4))) float  f32x4;
union Frag8 { bf16x8 v; unsigned short s[8]; uint4 q; };

// fp32 -> bf16 round-to-nearest-even
static __device__ __forceinline__ unsigned short f2bf(float f) {
    uint32 u = __float_as_uint(f);
    u += 0x7fffu + ((u >> 16) & 1u);
    return (unsigned short)(u >> 16);
}

// ---------------------------------------------------------------------------
// K0: Wt[n][k] = bf16(W[k][n])  (16 KB, built once; gemm B-frags read it)
// ---------------------------------------------------------------------------
__global__ __launch_bounds__(256) void w_transpose(const float* __restrict__ W,
                                                   ushort16* __restrict__ Wt) {
    const int base = blockIdx.x * 1024 + threadIdx.x;
#pragma unroll
    for (int j = 0; j < 4; ++j) {
        const int idx = base + j * 256;
        const int k = idx >> 6, n = idx & 63;
        Wt[n * N_FEAT + k] = f2bf(W[idx]);
    }
}

// ---------------------------------------------------------------------------
// K1: h = x @ W via MFMA (bf16 in, fp32 acc, bf16 out). No LDS, no barriers.
// Wave computes a 16-row x 64-col slab: 4 n-tiles x 4 k-chunks of
// mfma_f32_16x16x32_bf16. A loaded from x (fp32->bf16 in-reg), B from Wt
// (L1-hot 16 KB). Layouts (guide-verified): A[m=lane&15][k=quad*8+j],
// B[k=quad*8+j][n=lane&15], D col=lane&15 row=quad*4+reg.
// ---------------------------------------------------------------------------
__global__ __launch_bounds__(256) void gemm_xw(const float* __restrict__ x,
                                               const ushort16* __restrict__ Wt,
                                               ushort16* __restrict__ hb) {
    const int lane = threadIdx.x & 63;
    const int wv   = threadIdx.x >> 6;
    const int m15  = lane & 15;
    const int quad = lane >> 4;
    const int base = blockIdx.x * 64 + wv * 16;          // 16 rows per wave
    const int arow = min(base + m15, N_NODES - 1);       // clamp tail (stores guarded)

    const float* xr = &x[(size_t)arow * N_FEAT + quad * 8];
    float4 xa[4][2];
#pragma unroll
    for (int kc = 0; kc < 4; ++kc) {
        xa[kc][0] = *(const float4*)&xr[kc * 32];
        xa[kc][1] = *(const float4*)&xr[kc * 32 + 4];
    }

    Frag8 bf[4][4];
#pragma unroll
    for (int nt = 0; nt < 4; ++nt) {
        const ushort16* wr = &Wt[(nt * 16 + m15) * N_FEAT + quad * 8];
#pragma unroll
        for (int kc = 0; kc < 4; ++kc)
            bf[nt][kc].q = *(const uint4*)&wr[kc * 32];
    }

    Frag8 af[4];
#pragma unroll
    for (int kc = 0; kc < 4; ++kc) {
        const float* f = (const float*)&xa[kc][0];
#pragma unroll
        for (int j = 0; j < 8; ++j) af[kc].s[j] = f2bf(f[j]);
    }

    f32x4 acc[4];
#pragma unroll
    for (int nt = 0; nt < 4; ++nt) acc[nt] = (f32x4){0.f, 0.f, 0.f, 0.f};

#pragma unroll
    for (int kc = 0; kc < 4; ++kc)
#pragma unroll
        for (int nt = 0; nt < 4; ++nt)
            acc[nt] = __builtin_amdgcn_mfma_f32_16x16x32_bf16(af[kc].v, bf[nt][kc].v,
                                                              acc[nt], 0, 0, 0);

#pragma unroll
    for (int r = 0; r < 4; ++r) {
        const int orow = base + quad * 4 + r;
        if (orow < N_NODES) {
#pragma unroll
            for (int nt = 0; nt < 4; ++nt)
                hb[(size_t)orow * HIDDEN + nt * 16 + m15] = f2bf(acc[nt][r]);
        }
    }
}

// ---------------------------------------------------------------------------
// K2: partition edges into 391 dst-buckets per 8192-edge chunk via LDS; all
// global writes coalesced. dst stored as uint8 in-bucket id. Accumulates
// bucket sizes (bucket_size pre-zeroed).
// ---------------------------------------------------------------------------
__global__ __launch_bounds__(512) void partition_kernel(const int* __restrict__ ei,
                                                        int* __restrict__ src_out,
                                                        unsigned char* __restrict__ dst8,
                                                        int* __restrict__ offs,
                                                        int* __restrict__ bucket_size) {
    __shared__ int hist[512];
    __shared__ int excl[512];
    __shared__ int ssrc[CHUNK];     // 32 KB
    __shared__ int sdst[CHUNK];     // 32 KB
    const int c = blockIdx.x;
    const int base = c * CHUNK;
    const int n = min(CHUNK, N_EDGES - base);   // always a multiple of 4
    const int t = threadIdx.x;
    hist[t] = 0;
    __syncthreads();

    int es[CHUNK / 512], ed[CHUNK / 512], rk[CHUNK / 512];
#pragma unroll
    for (int k = 0; k < CHUNK / 512; ++k) {
        const int i = t + k * 512;
        if (i < n) {
            ed[k] = __builtin_nontemporal_load(&ei[N_EDGES + base + i]);
            es[k] = __builtin_nontemporal_load(&ei[base + i]);
            rk[k] = atomicAdd(&hist[ed[k] >> BSHIFT], 1);
        }
    }
    __syncthreads();

    const int cnt = hist[t];
    for (int off = 1; off < 512; off <<= 1) {
        const int v = (t >= off) ? hist[t - off] : 0;
        __syncthreads();
        hist[t] += v;
        __syncthreads();
    }
    excl[t] = hist[t] - cnt;
    __syncthreads();
    if (t <= NBUCKET) offs[c * OFFS_W + t] = base + excl[t];   // excl[NBUCKET]==n
    if (t < NBUCKET && cnt > 0) atomicAdd(&bucket_size[t], cnt);

#pragma unroll
    for (int k = 0; k < CHUNK / 512; ++k) {
        const int i = t + k * 512;
        if (i < n) {
            const int pos = excl[ed[k] >> BSHIFT] + rk[k];
            ssrc[pos] = es[k];
            sdst[pos] = ed[k];
        }
    }
    __syncthreads();

    for (int i = t; i < n; i += 512)
        src_out[base + i] = ssrc[i];
    for (int i = t * 4; i < n; i += 2048) {
        const uint32 p = (uint32)(sdst[i] & 255)
                       | ((uint32)(sdst[i + 1] & 255) << 8)
                       | ((uint32)(sdst[i + 2] & 255) << 16)
                       | ((uint32)(sdst[i + 3] & 255) << 24);
        *(uint32*)&dst8[base + i] = p;
    }
}

// ---------------------------------------------------------------------------
// K3: exclusive scan of bucket_size -> bucket_start (1 block).
// ---------------------------------------------------------------------------
__global__ __launch_bounds__(512) void scan_buckets(const int* __restrict__ bucket_size,
                                                    int* __restrict__ bucket_start) {
    __shared__ int s[512];
    const int t = threadIdx.x;
    const int v = (t < NBUCKET) ? bucket_size[t] : 0;
    s[t] = v;
    __syncthreads();
    for (int off = 1; off < 512; off <<= 1) {
        const int a = (t >= off) ? s[t - off] : 0;
        __syncthreads();
        s[t] += a;
        __syncthreads();
    }
    if (t < NBUCKET) bucket_start[t] = s[t] - v;
}

// ---------------------------------------------------------------------------
// K4: per-bucket CSR finalize (pass1 hist -> row_ptr/row_end/dis; pass2
// scatter src into the block-private window, combining in the owning CU's L2).
// ---------------------------------------------------------------------------
__global__ __launch_bounds__(512) void bucket_csr(const int* __restrict__ offs,
                                                  const int* __restrict__ src_tmp,
                                                  const unsigned char* __restrict__ dst8,
                                                  const int* __restrict__ bucket_start,
                                                  int* __restrict__ srcs,
                                                  int* __restrict__ row_ptr,
                                                  int* __restrict__ row_end,
                                                  float* __restrict__ dis) {
    __shared__ int hist[256];
    __shared__ int nxt[256];
    __shared__ int segb[NCHUNK], sege[NCHUNK];
    const int b = blockIdx.x;
    const int lo = b << BSHIFT;
    const int t = threadIdx.x;
    const int lane = t & 63;
    const int wv = t >> 6;                      // 8 waves
    const int bstart = bucket_start[b];

    if (t < 256) hist[t] = 0;
    for (int c = t; c < NCHUNK; c += 512) {
        segb[c] = offs[c * OFFS_W + b];
        sege[c] = offs[c * OFFS_W + b + 1];
    }
    __syncthreads();

    for (int c = wv; c < NCHUNK; c += 8)
        for (int i = segb[c] + lane; i < sege[c]; i += 64)
            atomicAdd(&hist[dst8[i]], 1);
    __syncthreads();

    const int cnt = (t < 256) ? hist[t] : 0;
    for (int off = 1; off < 256; off <<= 1) {
        int v = 0;
        if (t < 256 && t >= off) v = hist[t - off];
        __syncthreads();
        if (t < 256) hist[t] += v;
        __syncthreads();
    }
    if (t < 256) {
        const int excl = hist[t] - cnt;
        nxt[t] = excl;
        const int node = lo + t;
        if (node < N_NODES) {
            row_ptr[node] = bstart + excl;
            row_end[node] = bstart + excl + cnt;
            dis[node]     = rsqrtf((float)cnt + 1.0f);
        }
    }
    __syncthreads();

    for (int c = wv; c < NCHUNK; c += 8)
        for (int i = segb[c] + lane; i < sege[c]; i += 64) {
            const int d = dst8[i];
            const int s = src_tmp[i];
            const int pos = atomicAdd(&nxt[d], 1);
            srcs[bstart + pos] = s;
        }
}

// ---------------------------------------------------------------------------
// K5: gather-aggregate, 8 nodes per wave. BRANCHLESS inner loop: all 8
// gathers issue unconditionally (indices clamped into the valid window, so
// extra loads are harmless duplicates); validity is applied by zeroing the
// weight (v_cmp+cndmask). This keeps 16 lines in flight per 8-edge group
// instead of a serial exec-masked chain (R12: divergent `if` per gather).
// ---------------------------------------------------------------------------
__global__ __launch_bounds__(256) void agg_kernel(const int* __restrict__ row_ptr,
                                                  const int* __restrict__ row_end,
                                                  const int* __restrict__ srcs,
                                                  const ushort16* __restrict__ hb,
                                                  const float* __restrict__ dis,
                                                  const float* __restrict__ bias,
                                                  const int* __restrict__ batch,
                                                  float* __restrict__ u) {
    __shared__ float sp[32][HIDDEN + 1];   // pad 65: write banks differ per g
    __shared__ int gbs[32];
    const int t = threadIdx.x;
    const int lane = t & 63;
    const int wv = t >> 6;
    const int g = lane >> 3;
    const int k = lane & 7;
    const int kb = lane & 56;              // g*8, shfl source base
    const int base = blockIdx.x * 32;
    const int node = base + wv * 8 + g;    // N_NODES = 32*3125 exactly
    const int beg = row_ptr[node];
    const int end = row_end[node];
    const int deg = end - beg;
    const float dn = dis[node];

    int dmax = deg;
    dmax = max(dmax, __shfl_xor(dmax, 8));
    dmax = max(dmax, __shfl_xor(dmax, 16));
    dmax = max(dmax, __shfl_xor(dmax, 32));

    float acc[8];
#pragma unroll
    for (int j = 0; j < 8; ++j) acc[j] = 0.f;

    for (int i0 = 0; i0 < dmax; i0 += 8) {
        // fetch 8 edges per group (clamped; invalid lanes load duplicates)
        int idx = beg + i0 + k;
        idx = min(idx, end - 1);
        idx = max(idx, 0);
        const int s8 = srcs[idx];
        const float w8 = dis[s8] * dn;

        // phase 1: broadcast indices + predicated weights (no branches)
        int   si[8];
        float wi[8];
#pragma unroll
        for (int j = 0; j < 8; ++j) {
            si[j] = __shfl(s8, kb | j);
            const float w = __shfl(w8, kb | j);
            wi[j] = (i0 + j < deg) ? w : 0.f;
        }
        // phase 2: all 8 gathers issue back-to-back
        uint4 v[8];
#pragma unroll
        for (int j = 0; j < 8; ++j)
            v[j] = *(const uint4*)&hb[(size_t)si[j] * HIDDEN + k * 8];
        // phase 3: FMAs
#pragma unroll
        for (int j = 0; j < 8; ++j) {
            acc[0] = fmaf(__uint_as_float(v[j].x << 16),         wi[j], acc[0]);
            acc[1] = fmaf(__uint_as_float(v[j].x & 0xffff0000u), wi[j], acc[1]);
            acc[2] = fmaf(__uint_as_float(v[j].y << 16),         wi[j], acc[2]);
            acc[3] = fmaf(__uint_as_float(v[j].y & 0xffff0000u), wi[j], acc[3]);
            acc[4] = fmaf(__uint_as_float(v[j].z << 16),         wi[j], acc[4]);
            acc[5] = fmaf(__uint_as_float(v[j].z & 0xffff0000u), wi[j], acc[5]);
            acc[6] = fmaf(__uint_as_float(v[j].w << 16),         wi[j], acc[6]);
            acc[7] = fmaf(__uint_as_float(v[j].w & 0xffff0000u), wi[j], acc[7]);
        }
    }

    // self-loop + bias + relu, stage to LDS
    {
        const uint4 hv = *(const uint4*)&hb[(size_t)node * HIDDEN + k * 8];
        const float d2 = dn * dn;
        const float4 b0 = *(const float4*)&bias[k * 8];
        const float4 b1 = *(const float4*)&bias[k * 8 + 4];
        float4 r0, r1;
        r0.x = fmaxf(fmaf(__uint_as_float(hv.x << 16),         d2, acc[0]) + b0.x, 0.f);
        r0.y = fmaxf(fmaf(__uint_as_float(hv.x & 0xffff0000u), d2, acc[1]) + b0.y, 0.f);
        r0.z = fmaxf(fmaf(__uint_as_float(hv.y << 16),         d2, acc[2]) + b0.z, 0.f);
        r0.w = fmaxf(fmaf(__uint_as_float(hv.y & 0xffff0000u), d2, acc[3]) + b0.w, 0.f);
        r1.x = fmaxf(fmaf(__uint_as_float(hv.z << 16),         d2, acc[4]) + b1.x, 0.f);
        r1.y = fmaxf(fmaf(__uint_as_float(hv.z & 0xffff0000u), d2, acc[5]) + b1.y, 0.f);
        r1.z = fmaxf(fmaf(__uint_as_float(hv.w << 16),         d2, acc[6]) + b1.z, 0.f);
        r1.w = fmaxf(fmaf(__uint_as_float(hv.w & 0xffff0000u), d2, acc[7]) + b1.w, 0.f);
        *(float4*)&sp[wv * 8 + g][k * 8]     = r0;
        *(float4*)&sp[wv * 8 + g][k * 8 + 4] = r1;
    }
    if (t < 32) gbs[t] = batch[base + t];
    __syncthreads();

    // pool the 32 staged rows (batch sorted -> few runs)
    if (t < 64) {
        float a = sp[0][t];
        int cg = gbs[0];
        for (int r = 1; r < 32; ++r) {
            const int gr = gbs[r];
            const float vv = sp[r][t];
            if (gr == cg) a += vv;
            else { atomicAdd(&u[cg * HIDDEN + t], a); cg = gr; a = vv; }
        }
        atomicAdd(&u[cg * HIDDEN + t], a);
    }
}

// ---------------------------------------------------------------------------
// K6: out[g] = relu(u[g] @ W1 + b1) @ W2 + b2
// ---------------------------------------------------------------------------
__global__ __launch_bounds__(64) void mlp_kernel(const float* __restrict__ u,
                                                 const float* __restrict__ W1,
                                                 const float* __restrict__ b1,
                                                 const float* __restrict__ W2,
                                                 const float* __restrict__ b2,
                                                 float* __restrict__ out) {
    __shared__ float W1s[HIDDEN * 16];
    __shared__ float W2s[16];
    __shared__ float b1s[16];
    const int t = threadIdx.x;
    for (int i = t; i < HIDDEN * 16; i += 64) W1s[i] = W1[i];
    if (t < 16) { W2s[t] = W2[t]; b1s[t] = b1[t]; }
    __syncthreads();
    if (t < NUM_GRAPHS) {
        float uu[HIDDEN];
#pragma unroll
        for (int k = 0; k < HIDDEN; ++k) uu[k] = u[t * HIDDEN + k];
        float o = b2[0];
#pragma unroll
        for (int j = 0; j < 16; ++j) {
            float s = b1s[j];
#pragma unroll
            for (int k = 0; k < HIDDEN; ++k) s = fmaf(uu[k], W1s[k * 16 + j], s);
            o = fmaf(fmaxf(s, 0.f), W2s[j], o);
        }
        out[t] = o;
    }
}

// ---------------------------------------------------------------------------
extern "C" void kernel_launch(void* const* d_in, const int* in_sizes, int n_in,
                              void* d_out, int out_size, void* d_ws, size_t ws_size,
                              hipStream_t stream) {
    const float* x  = (const float*)d_in[0];
    const float* W  = (const float*)d_in[1];
    const float* b  = (const float*)d_in[2];
    const float* W1 = (const float*)d_in[3];
    const float* b1 = (const float*)d_in[4];
    const float* W2 = (const float*)d_in[5];
    const float* b2 = (const float*)d_in[6];
    const int*   ei = (const int*)d_in[7];     // [2, E] flat
    const int* batch = (const int*)d_in[8];    // [N], sorted
    float* out = (float*)d_out;

    ushort16* hb       = (ushort16*)d_ws;
    int*      src_tmp  = (int*)(hb + (size_t)N_NODES * HIDDEN);
    unsigned char* dst8 = (unsigned char*)(src_tmp + N_EDGES);
    int*      srcs     = (int*)(dst8 + N_EDGES);      // E multiple of 4 -> aligned
    int*      offs     = srcs + N_EDGES;
    int*      row_ptr  = offs + NCHUNK * OFFS_W;
    int*      row_end  = row_ptr + N_NODES;
    float*    dis      = (float*)(row_end + N_NODES);
    int*      bucket_size  = (int*)(dis + N_NODES);
    int*      bucket_start = bucket_size + 512;
    float*    u        = (float*)(bucket_start + 512);
    ushort16* Wtg      = (ushort16*)(u + NUM_GRAPHS * HIDDEN);   // 64x128 bf16

    hipMemsetAsync(bucket_size, 0, 512 * sizeof(int), stream);
    hipMemsetAsync(u, 0, NUM_GRAPHS * HIDDEN * sizeof(float), stream);

    w_transpose<<<8, 256, 0, stream>>>(W, Wtg);
    gemm_xw<<<(N_NODES + 63) / 64, 256, 0, stream>>>(x, Wtg, hb);
    partition_kernel<<<NCHUNK, 512, 0, stream>>>(ei, src_tmp, dst8, offs, bucket_size);
    scan_buckets<<<1, 512, 0, stream>>>(bucket_size, bucket_start);
    bucket_csr<<<NBUCKET, 512, 0, stream>>>(offs, src_tmp, dst8, bucket_start,
                                            srcs, row_ptr, row_end, dis);
    agg_kernel<<<N_NODES / 32, 256, 0, stream>>>(row_ptr, row_end, srcs, hb, dis, b, batch, u);
    mlp_kernel<<<1, 64, 0, stream>>>(u, W1, b1, W2, b2, out);
}

// Round 14
// 188.809 us; speedup vs baseline: 1.4240x; 1.0901x over previous
//
#include <hip/hip_runtime.h>

#define N_NODES   100000
#define N_FEAT    128
#define N_EDGES   1600000
#define HIDDEN    64
#define NUM_GRAPHS 64
#define CHUNK   8192
#define NCHUNK  ((N_EDGES + CHUNK - 1) / CHUNK)   // 196
#define BSHIFT  8
#define NBUCKET ((N_NODES + 255) >> 8)            // 391 buckets of 256 nodes
#define OFFS_W  (NBUCKET + 1)                     // 392 entries per chunk
#define CAP     4800                              // max bucket size (mean 4092 + 11 sigma)

typedef unsigned int  uint32;
typedef unsigned short ushort16;

typedef __attribute__((ext_vector_type(8))) __bf16 bf16x8;
typedef __attribute__((ext_vector_type(4))) float  f32x4;
union Frag8 { bf16x8 v; unsigned short s[8]; uint4 q; };

// fp32 -> bf16 round-to-nearest-even
static __device__ __forceinline__ unsigned short f2bf(float f) {
    uint32 u = __float_as_uint(f);
    u += 0x7fffu + ((u >> 16) & 1u);
    return (unsigned short)(u >> 16);
}

// ---------------------------------------------------------------------------
// K0: Wt[n][k] = bf16(W[k][n])  (16 KB, built once; gemm B-frags read it)
// ---------------------------------------------------------------------------
__global__ __launch_bounds__(256) void w_transpose(const float* __restrict__ W,
                                                   ushort16* __restrict__ Wt) {
    const int base = blockIdx.x * 1024 + threadIdx.x;
#pragma unroll
    for (int j = 0; j < 4; ++j) {
        const int idx = base + j * 256;
        const int k = idx >> 6, n = idx & 63;
        Wt[n * N_FEAT + k] = f2bf(W[idx]);
    }
}

// ---------------------------------------------------------------------------
// K1: h = x @ W via MFMA (bf16 in, fp32 acc, bf16 out). No LDS, no barriers.
// Wave computes a 16-row x 64-col slab: 4 n-tiles x 4 k-chunks of
// mfma_f32_16x16x32_bf16. Layouts (guide-verified): A[m=lane&15][k=quad*8+j],
// B[k=quad*8+j][n=lane&15], D col=lane&15 row=quad*4+reg.
// ---------------------------------------------------------------------------
__global__ __launch_bounds__(256) void gemm_xw(const float* __restrict__ x,
                                               const ushort16* __restrict__ Wt,
                                               ushort16* __restrict__ hb) {
    const int lane = threadIdx.x & 63;
    const int wv   = threadIdx.x >> 6;
    const int m15  = lane & 15;
    const int quad = lane >> 4;
    const int base = blockIdx.x * 64 + wv * 16;          // 16 rows per wave
    const int arow = min(base + m15, N_NODES - 1);       // clamp tail (stores guarded)

    const float* xr = &x[(size_t)arow * N_FEAT + quad * 8];
    float4 xa[4][2];
#pragma unroll
    for (int kc = 0; kc < 4; ++kc) {
        xa[kc][0] = *(const float4*)&xr[kc * 32];
        xa[kc][1] = *(const float4*)&xr[kc * 32 + 4];
    }

    Frag8 bf[4][4];
#pragma unroll
    for (int nt = 0; nt < 4; ++nt) {
        const ushort16* wr = &Wt[(nt * 16 + m15) * N_FEAT + quad * 8];
#pragma unroll
        for (int kc = 0; kc < 4; ++kc)
            bf[nt][kc].q = *(const uint4*)&wr[kc * 32];
    }

    Frag8 af[4];
#pragma unroll
    for (int kc = 0; kc < 4; ++kc) {
        const float* f = (const float*)&xa[kc][0];
#pragma unroll
        for (int j = 0; j < 8; ++j) af[kc].s[j] = f2bf(f[j]);
    }

    f32x4 acc[4];
#pragma unroll
    for (int nt = 0; nt < 4; ++nt) acc[nt] = (f32x4){0.f, 0.f, 0.f, 0.f};

#pragma unroll
    for (int kc = 0; kc < 4; ++kc)
#pragma unroll
        for (int nt = 0; nt < 4; ++nt)
            acc[nt] = __builtin_amdgcn_mfma_f32_16x16x32_bf16(af[kc].v, bf[nt][kc].v,
                                                              acc[nt], 0, 0, 0);

#pragma unroll
    for (int r = 0; r < 4; ++r) {
        const int orow = base + quad * 4 + r;
        if (orow < N_NODES) {
#pragma unroll
            for (int nt = 0; nt < 4; ++nt)
                hb[(size_t)orow * HIDDEN + nt * 16 + m15] = f2bf(acc[nt][r]);
        }
    }
}

// ---------------------------------------------------------------------------
// K2: partition edges into 391 dst-buckets per 8192-edge chunk via LDS; all
// global writes coalesced. dst stored as uint8 in-bucket id. (bucket sizes
// now derived in bucket_csr from offs -- no global atomics here.)
// ---------------------------------------------------------------------------
__global__ __launch_bounds__(512) void partition_kernel(const int* __restrict__ ei,
                                                        int* __restrict__ src_out,
                                                        unsigned char* __restrict__ dst8,
                                                        int* __restrict__ offs) {
    __shared__ int hist[512];
    __shared__ int excl[512];
    __shared__ int ssrc[CHUNK];     // 32 KB
    __shared__ int sdst[CHUNK];     // 32 KB
    const int c = blockIdx.x;
    const int base = c * CHUNK;
    const int n = min(CHUNK, N_EDGES - base);   // always a multiple of 4
    const int t = threadIdx.x;
    hist[t] = 0;
    __syncthreads();

    int es[CHUNK / 512], ed[CHUNK / 512], rk[CHUNK / 512];
#pragma unroll
    for (int k = 0; k < CHUNK / 512; ++k) {
        const int i = t + k * 512;
        if (i < n) {
            ed[k] = __builtin_nontemporal_load(&ei[N_EDGES + base + i]);
            es[k] = __builtin_nontemporal_load(&ei[base + i]);
            rk[k] = atomicAdd(&hist[ed[k] >> BSHIFT], 1);
        }
    }
    __syncthreads();

    const int cnt = hist[t];
    for (int off = 1; off < 512; off <<= 1) {
        const int v = (t >= off) ? hist[t - off] : 0;
        __syncthreads();
        hist[t] += v;
        __syncthreads();
    }
    excl[t] = hist[t] - cnt;
    __syncthreads();
    if (t <= NBUCKET) offs[c * OFFS_W + t] = base + excl[t];   // excl[NBUCKET]==n

#pragma unroll
    for (int k = 0; k < CHUNK / 512; ++k) {
        const int i = t + k * 512;
        if (i < n) {
            const int pos = excl[ed[k] >> BSHIFT] + rk[k];
            ssrc[pos] = es[k];
            sdst[pos] = ed[k];
        }
    }
    __syncthreads();

    for (int i = t; i < n; i += 512)
        src_out[base + i] = ssrc[i];
    for (int i = t * 4; i < n; i += 2048) {
        const uint32 p = (uint32)(sdst[i] & 255)
                       | ((uint32)(sdst[i + 1] & 255) << 8)
                       | ((uint32)(sdst[i + 2] & 255) << 16)
                       | ((uint32)(sdst[i + 3] & 255) << 24);
        *(uint32*)&dst8[base + i] = p;
    }
}

// ---------------------------------------------------------------------------
// K3: per-bucket CSR finalize, SINGLE PASS. Block b owns nodes
// [b*256, b*256+256). bucket_start is closed-form from offs:
//   bstart(b) = sum_c (offs[c][b] - c*CHUNK)   (computed via LDS reduction).
// Balanced edge distribution: segment-length prefix (LDS) + binary search
// gives thread t edges t, t+512, ... regardless of segment fragmentation.
// One global read pass; rank from LDS hist atomic; scatter into LDS; then
// coalesced writeout. Fallback to 2-pass scattered writes if bucket > CAP.
// ---------------------------------------------------------------------------
__global__ __launch_bounds__(512) void bucket_csr(const int* __restrict__ offs,
                                                  const int* __restrict__ src_tmp,
                                                  const unsigned char* __restrict__ dst8,
                                                  int* __restrict__ srcs,
                                                  int* __restrict__ row_ptr,
                                                  int* __restrict__ row_end,
                                                  float* __restrict__ dis) {
    __shared__ int hist[256];
    __shared__ int nxt[256];
    __shared__ int segb[NCHUNK];
    __shared__ int pre[NCHUNK + 1];
    __shared__ int sc[256];
    __shared__ int ssrc[CAP];       // 18.75 KB staging
    __shared__ int sb;
    const int b = blockIdx.x;
    const int lo = b << BSHIFT;
    const int t = threadIdx.x;

    if (t < 256) hist[t] = 0;
    if (t == 0) sb = 0;
    __syncthreads();

    int len = 0;
    if (t < NCHUNK) {
        const int s0 = offs[t * OFFS_W + b];
        const int s1 = offs[t * OFFS_W + b + 1];
        segb[t] = s0;
        len = s1 - s0;
        atomicAdd(&sb, s0 - t * CHUNK);     // closed-form bucket_start
    }
    if (t < 256) sc[t] = (t < NCHUNK) ? len : 0;
    __syncthreads();
    for (int off = 1; off < 256; off <<= 1) {
        int v = 0;
        if (t < 256 && t >= off) v = sc[t - off];
        __syncthreads();
        if (t < 256) sc[t] += v;
        __syncthreads();
    }
    if (t == 0) pre[0] = 0;
    if (t < NCHUNK) pre[t + 1] = sc[t];
    __syncthreads();

    const int total  = pre[NCHUNK];
    const int bstart = sb;
    const bool fits  = (total <= CAP);      // block-uniform

    int es[(CAP + 511) / 512], ed[(CAP + 511) / 512], rk[(CAP + 511) / 512];
    int ne = 0;
    if (fits) {
        for (int e = t; e < total; e += 512) {
            int l2 = 0, h2 = NCHUNK;
            while (h2 - l2 > 1) { const int mid = (l2 + h2) >> 1;
                                  if (pre[mid] <= e) l2 = mid; else h2 = mid; }
            const int gidx = segb[l2] + (e - pre[l2]);
            const int d = dst8[gidx];
            const int s = src_tmp[gidx];
            es[ne] = s; ed[ne] = d;
            rk[ne] = atomicAdd(&hist[d], 1);
            ++ne;
        }
    } else {                                 // fallback: count pass (rare)
        const int lane = t & 63, wv = t >> 6;
        for (int c = wv; c < NCHUNK; c += 8)
            for (int i = segb[c] + lane; i < segb[c] + (pre[c + 1] - pre[c]); i += 64)
                atomicAdd(&hist[dst8[i]], 1);
    }
    __syncthreads();

    const int cnt = (t < 256) ? hist[t] : 0;
    for (int off = 1; off < 256; off <<= 1) {
        int v = 0;
        if (t < 256 && t >= off) v = hist[t - off];
        __syncthreads();
        if (t < 256) hist[t] += v;
        __syncthreads();
    }
    if (t < 256) {
        const int excl = hist[t] - cnt;
        nxt[t] = excl;
        const int node = lo + t;
        if (node < N_NODES) {
            row_ptr[node] = bstart + excl;
            row_end[node] = bstart + excl + cnt;
            dis[node]     = rsqrtf((float)cnt + 1.0f);
        }
    }
    __syncthreads();

    if (fits) {
        for (int k = 0; k < ne; ++k)
            ssrc[nxt[ed[k]] + rk[k]] = es[k];   // LDS scatter
        __syncthreads();
        for (int i = t; i < total; i += 512)    // coalesced writeout
            srcs[bstart + i] = ssrc[i];
    } else {
        const int lane = t & 63, wv = t >> 6;
        for (int c = wv; c < NCHUNK; c += 8)
            for (int i = segb[c] + lane; i < segb[c] + (pre[c + 1] - pre[c]); i += 64) {
                const int d = dst8[i];
                const int pos = atomicAdd(&nxt[d], 1);
                srcs[bstart + pos] = src_tmp[i];
            }
    }
}

// ---------------------------------------------------------------------------
// K4: gather-aggregate, 8 nodes per wave, branchless inner loop (R13).
// ---------------------------------------------------------------------------
__global__ __launch_bounds__(256) void agg_kernel(const int* __restrict__ row_ptr,
                                                  const int* __restrict__ row_end,
                                                  const int* __restrict__ srcs,
                                                  const ushort16* __restrict__ hb,
                                                  const float* __restrict__ dis,
                                                  const float* __restrict__ bias,
                                                  const int* __restrict__ batch,
                                                  float* __restrict__ u) {
    __shared__ float sp[32][HIDDEN + 1];   // pad 65: write banks differ per g
    __shared__ int gbs[32];
    const int t = threadIdx.x;
    const int lane = t & 63;
    const int wv = t >> 6;
    const int g = lane >> 3;
    const int k = lane & 7;
    const int kb = lane & 56;              // g*8, shfl source base
    const int base = blockIdx.x * 32;
    const int node = base + wv * 8 + g;    // N_NODES = 32*3125 exactly
    const int beg = row_ptr[node];
    const int end = row_end[node];
    const int deg = end - beg;
    const float dn = dis[node];

    int dmax = deg;
    dmax = max(dmax, __shfl_xor(dmax, 8));
    dmax = max(dmax, __shfl_xor(dmax, 16));
    dmax = max(dmax, __shfl_xor(dmax, 32));

    float acc[8];
#pragma unroll
    for (int j = 0; j < 8; ++j) acc[j] = 0.f;

    for (int i0 = 0; i0 < dmax; i0 += 8) {
        int idx = beg + i0 + k;
        idx = min(idx, end - 1);
        idx = max(idx, 0);
        const int s8 = srcs[idx];
        const float w8 = dis[s8] * dn;

        int   si[8];
        float wi[8];
#pragma unroll
        for (int j = 0; j < 8; ++j) {
            si[j] = __shfl(s8, kb | j);
            const float w = __shfl(w8, kb | j);
            wi[j] = (i0 + j < deg) ? w : 0.f;
        }
        uint4 v[8];
#pragma unroll
        for (int j = 0; j < 8; ++j)
            v[j] = *(const uint4*)&hb[(size_t)si[j] * HIDDEN + k * 8];
#pragma unroll
        for (int j = 0; j < 8; ++j) {
            acc[0] = fmaf(__uint_as_float(v[j].x << 16),         wi[j], acc[0]);
            acc[1] = fmaf(__uint_as_float(v[j].x & 0xffff0000u), wi[j], acc[1]);
            acc[2] = fmaf(__uint_as_float(v[j].y << 16),         wi[j], acc[2]);
            acc[3] = fmaf(__uint_as_float(v[j].y & 0xffff0000u), wi[j], acc[3]);
            acc[4] = fmaf(__uint_as_float(v[j].z << 16),         wi[j], acc[4]);
            acc[5] = fmaf(__uint_as_float(v[j].z & 0xffff0000u), wi[j], acc[5]);
            acc[6] = fmaf(__uint_as_float(v[j].w << 16),         wi[j], acc[6]);
            acc[7] = fmaf(__uint_as_float(v[j].w & 0xffff0000u), wi[j], acc[7]);
        }
    }

    {
        const uint4 hv = *(const uint4*)&hb[(size_t)node * HIDDEN + k * 8];
        const float d2 = dn * dn;
        const float4 b0 = *(const float4*)&bias[k * 8];
        const float4 b1 = *(const float4*)&bias[k * 8 + 4];
        float4 r0, r1;
        r0.x = fmaxf(fmaf(__uint_as_float(hv.x << 16),         d2, acc[0]) + b0.x, 0.f);
        r0.y = fmaxf(fmaf(__uint_as_float(hv.x & 0xffff0000u), d2, acc[1]) + b0.y, 0.f);
        r0.z = fmaxf(fmaf(__uint_as_float(hv.y << 16),         d2, acc[2]) + b0.z, 0.f);
        r0.w = fmaxf(fmaf(__uint_as_float(hv.y & 0xffff0000u), d2, acc[3]) + b0.w, 0.f);
        r1.x = fmaxf(fmaf(__uint_as_float(hv.z << 16),         d2, acc[4]) + b1.x, 0.f);
        r1.y = fmaxf(fmaf(__uint_as_float(hv.z & 0xffff0000u), d2, acc[5]) + b1.y, 0.f);
        r1.z = fmaxf(fmaf(__uint_as_float(hv.w << 16),         d2, acc[6]) + b1.z, 0.f);
        r1.w = fmaxf(fmaf(__uint_as_float(hv.w & 0xffff0000u), d2, acc[7]) + b1.w, 0.f);
        *(float4*)&sp[wv * 8 + g][k * 8]     = r0;
        *(float4*)&sp[wv * 8 + g][k * 8 + 4] = r1;
    }
    if (t < 32) gbs[t] = batch[base + t];
    __syncthreads();

    if (t < 64) {
        float a = sp[0][t];
        int cg = gbs[0];
        for (int r = 1; r < 32; ++r) {
            const int gr = gbs[r];
            const float vv = sp[r][t];
            if (gr == cg) a += vv;
            else { atomicAdd(&u[cg * HIDDEN + t], a); cg = gr; a = vv; }
        }
        atomicAdd(&u[cg * HIDDEN + t], a);
    }
}

// ---------------------------------------------------------------------------
// K5: out[g] = relu(u[g] @ W1 + b1) @ W2 + b2
// ---------------------------------------------------------------------------
__global__ __launch_bounds__(64) void mlp_kernel(const float* __restrict__ u,
                                                 const float* __restrict__ W1,
                                                 const float* __restrict__ b1,
                                                 const float* __restrict__ W2,
                                                 const float* __restrict__ b2,
                                                 float* __restrict__ out) {
    __shared__ float W1s[HIDDEN * 16];
    __shared__ float W2s[16];
    __shared__ float b1s[16];
    const int t = threadIdx.x;
    for (int i = t; i < HIDDEN * 16; i += 64) W1s[i] = W1[i];
    if (t < 16) { W2s[t] = W2[t]; b1s[t] = b1[t]; }
    __syncthreads();
    if (t < NUM_GRAPHS) {
        float uu[HIDDEN];
#pragma unroll
        for (int k = 0; k < HIDDEN; ++k) uu[k] = u[t * HIDDEN + k];
        float o = b2[0];
#pragma unroll
        for (int j = 0; j < 16; ++j) {
            float s = b1s[j];
#pragma unroll
            for (int k = 0; k < HIDDEN; ++k) s = fmaf(uu[k], W1s[k * 16 + j], s);
            o = fmaf(fmaxf(s, 0.f), W2s[j], o);
        }
        out[t] = o;
    }
}

// ---------------------------------------------------------------------------
extern "C" void kernel_launch(void* const* d_in, const int* in_sizes, int n_in,
                              void* d_out, int out_size, void* d_ws, size_t ws_size,
                              hipStream_t stream) {
    const float* x  = (const float*)d_in[0];
    const float* W  = (const float*)d_in[1];
    const float* b  = (const float*)d_in[2];
    const float* W1 = (const float*)d_in[3];
    const float* b1 = (const float*)d_in[4];
    const float* W2 = (const float*)d_in[5];
    const float* b2 = (const float*)d_in[6];
    const int*   ei = (const int*)d_in[7];     // [2, E] flat
    const int* batch = (const int*)d_in[8];    // [N], sorted
    float* out = (float*)d_out;

    ushort16* hb       = (ushort16*)d_ws;
    int*      src_tmp  = (int*)(hb + (size_t)N_NODES * HIDDEN);
    unsigned char* dst8 = (unsigned char*)(src_tmp + N_EDGES);
    int*      srcs     = (int*)(dst8 + N_EDGES);      // E multiple of 4 -> aligned
    int*      offs     = srcs + N_EDGES;
    int*      row_ptr  = offs + NCHUNK * OFFS_W;
    int*      row_end  = row_ptr + N_NODES;
    float*    dis      = (float*)(row_end + N_NODES);
    float*    u        = dis + N_NODES;
    ushort16* Wtg      = (ushort16*)(u + NUM_GRAPHS * HIDDEN);   // 64x128 bf16

    hipMemsetAsync(u, 0, NUM_GRAPHS * HIDDEN * sizeof(float), stream);

    w_transpose<<<8, 256, 0, stream>>>(W, Wtg);
    gemm_xw<<<(N_NODES + 63) / 64, 256, 0, stream>>>(x, Wtg, hb);
    partition_kernel<<<NCHUNK, 512, 0, stream>>>(ei, src_tmp, dst8, offs);
    bucket_csr<<<NBUCKET, 512, 0, stream>>>(offs, src_tmp, dst8,
                                            srcs, row_ptr, row_end, dis);
    agg_kernel<<<N_NODES / 32, 256, 0, stream>>>(row_ptr, row_end, srcs, hb, dis, b, batch, u);
    mlp_kernel<<<1, 64, 0, stream>>>(u, W1, b1, W2, b2, out);
}